// Round 2
// baseline (1106.821 us; speedup 1.0000x reference)
//
#include <hip/hip_runtime.h>
#include <cstdint>

#define RES    28
#define RES2   14
#define NHEAD  8
#define KDIM   16
#define DV     64
#define DHID   512
#define NSEQ   784
#define N2SEQ  196
#define BATCH  64
#define CIN    384

// ---------------------------------------------------------------------------
// Generic GEMM out[M,N] = (A[M,K] @ W[K,N] + bias[N]) * scale[N] + shift[N]
// BM=BN=64, BK=16, 256 threads, 4x4 microtile per thread.
// Requires M%64==0, N%64==0, K%16==0 (true for all our shapes).
// ---------------------------------------------------------------------------
#define BM 64
#define BN 64
#define BK 16

__global__ __launch_bounds__(256)
void gemm_bn_kernel(const float* __restrict__ A, const float* __restrict__ W,
                    const float* __restrict__ bias, const float* __restrict__ scale,
                    const float* __restrict__ shift, float* __restrict__ out,
                    int M, int N, int K)
{
    __shared__ float As[BK][BM + 4];   // +4 keeps rows 16B-aligned, breaks conflicts
    __shared__ float Bs[BK][BN + 4];

    const int t  = threadIdx.x;
    const int bm = blockIdx.x * BM;
    const int bn = blockIdx.y * BN;
    const int tx = t & 15;      // output col group (4 cols)
    const int ty = t >> 4;      // output row group (4 rows)

    // A-tile load coords: 64 rows x 16 k, one float4 per thread
    const int am = t >> 2;
    const int ak = (t & 3) * 4;
    // B-tile load coords: 16 k-rows x 64 cols, one float4 per thread
    const int bk  = t >> 4;
    const int bn4 = (t & 15) * 4;

    const float* Ag = A + (size_t)(bm + am) * K + ak;
    const float* Wg = W + (size_t)bk * N + (bn + bn4);

    float acc[4][4] = {};

    for (int k0 = 0; k0 < K; k0 += BK) {
        float4 a4 = *(const float4*)(Ag + k0);
        float4 b4 = *(const float4*)(Wg + (size_t)k0 * N);
        As[ak + 0][am] = a4.x;
        As[ak + 1][am] = a4.y;
        As[ak + 2][am] = a4.z;
        As[ak + 3][am] = a4.w;
        *(float4*)&Bs[bk][bn4] = b4;
        __syncthreads();
        #pragma unroll
        for (int kk = 0; kk < BK; ++kk) {
            float4 av = *(const float4*)&As[kk][ty * 4];
            float4 bv = *(const float4*)&Bs[kk][tx * 4];
            acc[0][0] += av.x * bv.x; acc[0][1] += av.x * bv.y;
            acc[0][2] += av.x * bv.z; acc[0][3] += av.x * bv.w;
            acc[1][0] += av.y * bv.x; acc[1][1] += av.y * bv.y;
            acc[1][2] += av.y * bv.z; acc[1][3] += av.y * bv.w;
            acc[2][0] += av.z * bv.x; acc[2][1] += av.z * bv.y;
            acc[2][2] += av.z * bv.z; acc[2][3] += av.z * bv.w;
            acc[3][0] += av.w * bv.x; acc[3][1] += av.w * bv.y;
            acc[3][2] += av.w * bv.z; acc[3][3] += av.w * bv.w;
        }
        __syncthreads();
    }

    const int n = bn + tx * 4;
    float4 bi = *(const float4*)(bias  + n);
    float4 sc = *(const float4*)(scale + n);
    float4 sh = *(const float4*)(shift + n);
    #pragma unroll
    for (int i = 0; i < 4; ++i) {
        const int m = bm + ty * 4 + i;
        float4 r;
        r.x = (acc[i][0] + bi.x) * sc.x + sh.x;
        r.y = (acc[i][1] + bi.y) * sc.y + sh.y;
        r.z = (acc[i][2] + bi.z) * sc.z + sh.z;
        r.w = (acc[i][3] + bi.w) * sc.w + sh.w;
        *(float4*)(out + (size_t)m * N + n) = r;
    }
}

// ---------------------------------------------------------------------------
// q_in[b,i,j,c] = dwconv3x3_stride2_SAME(x)[b,i,j,c] + q_local_b[c] + x[b,2i,2j,c]
// TF/JAX SAME, in=28, stride=2, k=3: pad=(0,1) -> window rows/cols 2i..2i+2.
// One float4 (4 channels) per thread.
// ---------------------------------------------------------------------------
__global__ __launch_bounds__(256)
void qin_kernel(const float* __restrict__ x, const float* __restrict__ w,
                const float* __restrict__ b, float* __restrict__ qin)
{
    const int C4 = CIN / 4;   // 96
    int idx = blockIdx.x * 256 + threadIdx.x;
    if (idx >= BATCH * RES2 * RES2 * C4) return;
    int c4 = idx % C4;
    int r  = idx / C4;
    int j  = r % RES2; r /= RES2;
    int i  = r % RES2;
    int bb = r / RES2;

    const float4* x4 = (const float4*)x;
    const float4* w4 = (const float4*)w;
    float4 acc = make_float4(0.f, 0.f, 0.f, 0.f);
    #pragma unroll
    for (int dy = 0; dy < 3; ++dy) {
        int iy = 2 * i + dy;
        if (iy >= RES) continue;
        #pragma unroll
        for (int dx = 0; dx < 3; ++dx) {
            int ix = 2 * j + dx;
            if (ix >= RES) continue;
            float4 xv = x4[((size_t)(bb * RES + iy) * RES + ix) * C4 + c4];
            float4 wv = w4[(dy * 3 + dx) * C4 + c4];
            acc.x += xv.x * wv.x; acc.y += xv.y * wv.y;
            acc.z += xv.z * wv.z; acc.w += xv.w * wv.w;
        }
    }
    float4 bv = ((const float4*)b)[c4];
    float4 xs = x4[((size_t)(bb * RES + 2 * i) * RES + 2 * j) * C4 + c4];
    acc.x += bv.x + xs.x; acc.y += bv.y + xs.y;
    acc.z += bv.z + xs.z; acc.w += bv.w + xs.w;
    ((float4*)qin)[idx] = acc;
}

// ---------------------------------------------------------------------------
// v_local[b,i,j,c] = (dwconv3x3_s2(v)[b,i,j,c] + vloc_b[c]) * s[c] + sh[c]
// ---------------------------------------------------------------------------
__global__ __launch_bounds__(256)
void vloc_kernel(const float* __restrict__ v, const float* __restrict__ w,
                 const float* __restrict__ b, const float* __restrict__ s,
                 const float* __restrict__ sh, float* __restrict__ out)
{
    const int C4 = DHID / 4;   // 128
    int idx = blockIdx.x * 256 + threadIdx.x;
    if (idx >= BATCH * RES2 * RES2 * C4) return;
    int c4 = idx % C4;
    int r  = idx / C4;
    int j  = r % RES2; r /= RES2;
    int i  = r % RES2;
    int bb = r / RES2;

    const float4* v4 = (const float4*)v;
    const float4* w4 = (const float4*)w;
    float4 acc = make_float4(0.f, 0.f, 0.f, 0.f);
    #pragma unroll
    for (int dy = 0; dy < 3; ++dy) {
        int iy = 2 * i + dy;
        if (iy >= RES) continue;
        #pragma unroll
        for (int dx = 0; dx < 3; ++dx) {
            int ix = 2 * j + dx;
            if (ix >= RES) continue;
            float4 xv = v4[((size_t)(bb * RES + iy) * RES + ix) * C4 + c4];
            float4 wv = w4[(dy * 3 + dx) * C4 + c4];
            acc.x += xv.x * wv.x; acc.y += xv.y * wv.y;
            acc.z += xv.z * wv.z; acc.w += xv.w * wv.w;
        }
    }
    float4 bv = ((const float4*)b)[c4];
    float4 sv = ((const float4*)s)[c4];
    float4 hv = ((const float4*)sh)[c4];
    acc.x = (acc.x + bv.x) * sv.x + hv.x;
    acc.y = (acc.y + bv.y) * sv.y + hv.y;
    acc.z = (acc.z + bv.z) * sv.z + hv.z;
    acc.w = (acc.w + bv.w) * sv.w + hv.w;
    ((float4*)out)[idx] = acc;
}

// ---------------------------------------------------------------------------
// Attention: one block per (b,h). Threads 0..195 each own one query row.
// Flash-style online softmax with conditional rescale; K/V tiles + bias row
// in LDS. Adds result in-place into io (which holds v_local on entry).
// rel bias index: |2*pj - kw|*28 + |2*pi - ku|  (meshgrid 'xy' construction).
// NOTE: NSEQ=784 = 12*64 + 16 -> last tile has only 16 valid keys; loads are
// clamped and the key loop bounded (unbounded loop was the round-1 bug:
// 48 phantom keys stole ~6% of softmax mass -> absmax 0.285).
// ---------------------------------------------------------------------------
__global__ __launch_bounds__(256)
void attn_kernel(const float* __restrict__ q, const float* __restrict__ k,
                 const float* __restrict__ v, const float* __restrict__ bias,
                 float* __restrict__ io)
{
    __shared__ float ks[64][16];
    __shared__ float vs[64][64];
    __shared__ float bsm[NSEQ];

    const int t  = threadIdx.x;
    const int bh = blockIdx.x;
    const int b  = bh >> 3;
    const int h  = bh & 7;

    for (int i = t; i < NSEQ; i += 256) bsm[i] = bias[h * NSEQ + i];

    float qr[16];
    float m = -1e30f, l = 0.f;
    float acc[64];
    #pragma unroll
    for (int d = 0; d < 64; ++d) acc[d] = 0.f;

    int pi = 0, pj = 0;
    if (t < N2SEQ) {
        pi = t / 14; pj = t % 14;
        const float* qp = q + ((size_t)b * N2SEQ + t) * (NHEAD * KDIM) + h * KDIM;
        #pragma unroll
        for (int d4 = 0; d4 < 4; ++d4) {
            float4 v4 = *(const float4*)(qp + d4 * 4);
            qr[d4 * 4 + 0] = v4.x; qr[d4 * 4 + 1] = v4.y;
            qr[d4 * 4 + 2] = v4.z; qr[d4 * 4 + 3] = v4.w;
        }
    }

    const float scl = 0.25f;   // KD^-0.5

    for (int t0 = 0; t0 < NSEQ; t0 += 64) {
        int nrows = NSEQ - t0; if (nrows > 64) nrows = 64;
        {   // K tile: 64 rows x 16 (row clamped for the partial last tile)
            int rr = t >> 2, cc = (t & 3) * 4;
            int gr = t0 + rr; if (gr >= NSEQ) gr = NSEQ - 1;
            float4 kv = *(const float4*)(k + ((size_t)b * NSEQ + gr) * (NHEAD * KDIM) + h * KDIM + cc);
            *(float4*)&ks[rr][cc] = kv;
        }
        #pragma unroll
        for (int it = 0; it < 4; ++it) {   // V tile: 64 rows x 64
            int idx = t + it * 256;
            int rr = idx >> 4, cc = (idx & 15) * 4;
            int gr = t0 + rr; if (gr >= NSEQ) gr = NSEQ - 1;
            float4 vv = *(const float4*)(v + ((size_t)b * NSEQ + gr) * DHID + h * DV + cc);
            *(float4*)&vs[rr][cc] = vv;
        }
        __syncthreads();

        if (t < N2SEQ) {
            int ku = t0 / 28, kw = t0 % 28;   // uniform across block
            for (int r = 0; r < nrows; ++r) {
                const float* kr = ks[r];
                float dot = 0.f;
                #pragma unroll
                for (int d = 0; d < 16; ++d) dot += qr[d] * kr[d];
                int d0 = 2 * pj - kw; if (d0 < 0) d0 = -d0;
                int d1 = 2 * pi - ku; if (d1 < 0) d1 = -d1;
                float lg = dot * scl + bsm[d0 * 28 + d1];
                if (lg > m) {
                    float al = __expf(m - lg);
                    m = lg;
                    l *= al;
                    #pragma unroll
                    for (int d = 0; d < 64; ++d) acc[d] *= al;
                }
                float p = __expf(lg - m);
                l += p;
                #pragma unroll
                for (int d4 = 0; d4 < 16; ++d4) {
                    float4 vv = *(const float4*)&vs[r][d4 * 4];
                    acc[d4 * 4 + 0] += p * vv.x;
                    acc[d4 * 4 + 1] += p * vv.y;
                    acc[d4 * 4 + 2] += p * vv.z;
                    acc[d4 * 4 + 3] += p * vv.w;
                }
                if (++kw == 28) { kw = 0; ++ku; }
            }
        }
        __syncthreads();
    }

    if (t < N2SEQ) {
        float inv = 1.0f / l;
        float* op = io + ((size_t)b * N2SEQ + t) * DHID + h * DV;
        #pragma unroll
        for (int d4 = 0; d4 < 16; ++d4) {
            float4 prev = *(const float4*)(op + d4 * 4);
            float4 r;
            r.x = acc[d4 * 4 + 0] * inv + prev.x;
            r.y = acc[d4 * 4 + 1] * inv + prev.y;
            r.z = acc[d4 * 4 + 2] * inv + prev.z;
            r.w = acc[d4 * 4 + 3] * inv + prev.w;
            *(float4*)(op + d4 * 4) = r;
        }
    }
}

// ---------------------------------------------------------------------------
extern "C" void kernel_launch(void* const* d_in, const int* in_sizes, int n_in,
                              void* d_out, int out_size, void* d_ws, size_t ws_size,
                              hipStream_t stream)
{
    const float* x          = (const float*)d_in[0];
    const float* q_local_w  = (const float*)d_in[1];
    const float* q_local_b  = (const float*)d_in[2];
    const float* q_proj_w   = (const float*)d_in[3];
    const float* q_proj_b   = (const float*)d_in[4];
    const float* q_bn_s     = (const float*)d_in[5];
    const float* q_bn_b     = (const float*)d_in[6];
    const float* k_w        = (const float*)d_in[7];
    const float* k_b        = (const float*)d_in[8];
    const float* k_bn_s     = (const float*)d_in[9];
    const float* k_bn_b     = (const float*)d_in[10];
    const float* v_w        = (const float*)d_in[11];
    const float* v_b        = (const float*)d_in[12];
    const float* v_bn_s     = (const float*)d_in[13];
    const float* v_bn_b     = (const float*)d_in[14];
    const float* vloc_w     = (const float*)d_in[15];
    const float* vloc_b     = (const float*)d_in[16];
    const float* vloc_bn_s  = (const float*)d_in[17];
    const float* vloc_bn_b  = (const float*)d_in[18];
    const float* proj_w     = (const float*)d_in[19];
    const float* proj_b     = (const float*)d_in[20];
    const float* proj_bn_s  = (const float*)d_in[21];
    const float* proj_bn_b  = (const float*)d_in[22];
    const float* attn_bias  = (const float*)d_in[23];
    float* out = (float*)d_out;

    const int M1 = BATCH * NSEQ;    // 50176 (28x28 tokens)
    const int M2 = BATCH * N2SEQ;   // 12544 (14x14 tokens)

    // Workspace layout (floats). Region A is time-shared: q_in (steps 1-4)
    // then vloc (steps 5-7) -- stream-ordered kernels make this safe.
    float* ws    = (float*)d_ws;
    float* q_in  = ws;                                  // 12544*384 = 4.82M
    float* vloc  = ws;                                  // 12544*512 = 6.42M (overlays q_in)
    float* regA_end = ws + (size_t)M2 * DHID;           // max of the two
    float* kbuf  = regA_end;                            // 50176*128
    float* vbuf  = kbuf + (size_t)M1 * (NHEAD * KDIM);  // 50176*512
    float* qbuf  = vbuf + (size_t)M1 * DHID;            // 12544*128

    // 1. q_in = dwconv(x) + b + subsample(x)
    {
        int items = M2 * (CIN / 4);
        qin_kernel<<<dim3((items + 255) / 256), 256, 0, stream>>>(x, q_local_w, q_local_b, q_in);
    }
    // 2. k = BN(x @ k_w + k_b)
    gemm_bn_kernel<<<dim3(M1 / BM, 128 / BN), 256, 0, stream>>>(
        x, k_w, k_b, k_bn_s, k_bn_b, kbuf, M1, 128, CIN);
    // 3. v = BN(x @ v_w + v_b)
    gemm_bn_kernel<<<dim3(M1 / BM, DHID / BN), 256, 0, stream>>>(
        x, v_w, v_b, v_bn_s, v_bn_b, vbuf, M1, DHID, CIN);
    // 4. q = BN(q_in @ q_proj_w + q_proj_b)
    gemm_bn_kernel<<<dim3(M2 / BM, 128 / BN), 256, 0, stream>>>(
        q_in, q_proj_w, q_proj_b, q_bn_s, q_bn_b, qbuf, M2, 128, CIN);
    // 5. v_local = BN(dwconv(v))  (overwrites region A; q_in is dead now)
    {
        int items = M2 * (DHID / 4);
        vloc_kernel<<<dim3((items + 255) / 256), 256, 0, stream>>>(
            vbuf, vloc_w, vloc_b, vloc_bn_s, vloc_bn_b, vloc);
    }
    // 6. attention, adds into vloc
    attn_kernel<<<dim3(BATCH * NHEAD), 256, 0, stream>>>(qbuf, kbuf, vbuf, attn_bias, vloc);
    // 7. out = BN(vloc @ proj_w + proj_b)
    gemm_bn_kernel<<<dim3(M2 / BM, 768 / BN), 256, 0, stream>>>(
        vloc, proj_w, proj_b, proj_bn_s, proj_bn_b, out, M2, 768, DHID);
}

// Round 3
// 665.514 us; speedup vs baseline: 1.6631x; 1.6631x over previous
//
#include <hip/hip_runtime.h>
#include <cstdint>

#define RES    28
#define RES2   14
#define NHEAD  8
#define KDIM   16
#define DV     64
#define DHID   512
#define NSEQ   784
#define N2SEQ  196
#define BATCH  64
#define CIN    384

typedef unsigned short u16;
typedef short  short8 __attribute__((ext_vector_type(8)));
typedef float  f32x4  __attribute__((ext_vector_type(4)));
typedef u16    us4    __attribute__((ext_vector_type(4)));
typedef u16    us8    __attribute__((ext_vector_type(8)));

__device__ __forceinline__ u16 f2bf(float f) {
    uint32_t u = __float_as_uint(f);
    return (u16)((u + 0x7fffu + ((u >> 16) & 1u)) >> 16);   // RNE
}
__device__ __forceinline__ float bf2f(u16 h) {
    return __uint_as_float(((uint32_t)h) << 16);
}

// ---------------------------------------------------------------------------
// fp32 -> bf16 cast, 4 elems/thread
// ---------------------------------------------------------------------------
__global__ __launch_bounds__(256)
void cast_bf16_kernel(const float* __restrict__ in, u16* __restrict__ out, int n4)
{
    int i = blockIdx.x * 256 + threadIdx.x;
    if (i >= n4) return;
    float4 v = ((const float4*)in)[i];
    us4 r;
    r.x = f2bf(v.x); r.y = f2bf(v.y); r.z = f2bf(v.z); r.w = f2bf(v.w);
    ((us4*)out)[i] = r;
}

// W[K,N] fp32 -> Wt[N,K] bf16 (small weight matrices only)
__global__ __launch_bounds__(256)
void castT_kernel(const float* __restrict__ W, u16* __restrict__ Wt, int K, int N)
{
    int i = blockIdx.x * 256 + threadIdx.x;
    if (i >= K * N) return;
    int n = i / K, k = i % K;
    Wt[i] = f2bf(W[(size_t)k * N + n]);
}

// ---------------------------------------------------------------------------
// MFMA GEMM: out[M,N] = epilogue(A[M,K] @ Wt[N,K]^T).  A, Wt bf16 (u16).
// 128x128 tile, BK=32, 256 threads = 4 waves in 2x2, each wave 64x64 via
// 4x4 grid of 16x16x32 bf16 MFMA. global_load_lds width-16 staging.
// OUT_BF16: epilogue stores bf16; else fp32. Requires M%128==0, N%128==0, K%32==0.
// ---------------------------------------------------------------------------
#define TM 128
#define TN 128
#define TK 32

template<int OUT_BF16>
__global__ __launch_bounds__(256)
void gemm_mfma_kernel(const u16* __restrict__ A, const u16* __restrict__ Bt,
                      const float* __restrict__ bias, const float* __restrict__ scale,
                      const float* __restrict__ shift, void* __restrict__ outp,
                      int M, int N, int K)
{
    __shared__ u16 As[TM * TK];   // [row][k] rows of 32 bf16 = 64B = 4 chunks
    __shared__ u16 Bs[TN * TK];

    const int t  = threadIdx.x;
    const int w  = t >> 6;        // wave id 0..3
    const int li = t & 63;        // lane
    const int wm = w >> 1, wn = w & 1;
    const int bm = blockIdx.x * TM;
    const int bn = blockIdx.y * TN;
    const int m16 = li & 15;      // frag row/col within 16
    const int kg  = li >> 4;      // k-group 0..3

    // staging coords: chunk c = (w*2+i)*64 + li covers 512 16B-chunks per tile
    f32x4 acc[4][4];
    #pragma unroll
    for (int i = 0; i < 4; ++i)
        #pragma unroll
        for (int j = 0; j < 4; ++j) acc[i][j] = (f32x4)0.0f;

    for (int k0 = 0; k0 < K; k0 += TK) {
        #pragma unroll
        for (int i = 0; i < 2; ++i) {
            int c   = (w * 2 + i) * 64 + li;
            int row = c >> 2, kc = c & 3;
            const u16* ag = A  + (size_t)(bm + row) * K + k0 + kc * 8;
            const u16* bg = Bt + (size_t)(bn + row) * K + k0 + kc * 8;
            char* la = (char*)As + (size_t)(w * 2 + i) * 64 * 16;
            char* lb = (char*)Bs + (size_t)(w * 2 + i) * 64 * 16;
            __builtin_amdgcn_global_load_lds(
                (const __attribute__((address_space(1))) void*)ag,
                (__attribute__((address_space(3))) void*)la, 16, 0, 0);
            __builtin_amdgcn_global_load_lds(
                (const __attribute__((address_space(1))) void*)bg,
                (__attribute__((address_space(3))) void*)lb, 16, 0, 0);
        }
        __syncthreads();

        short8 af[4], bf[4];
        #pragma unroll
        for (int mi = 0; mi < 4; ++mi)
            af[mi] = *(const short8*)&As[(wm * 64 + mi * 16 + m16) * TK + kg * 8];
        #pragma unroll
        for (int ni = 0; ni < 4; ++ni)
            bf[ni] = *(const short8*)&Bs[(wn * 64 + ni * 16 + m16) * TK + kg * 8];

        #pragma unroll
        for (int mi = 0; mi < 4; ++mi)
            #pragma unroll
            for (int ni = 0; ni < 4; ++ni)
                acc[mi][ni] = __builtin_amdgcn_mfma_f32_16x16x32_bf16(
                    af[mi], bf[ni], acc[mi][ni], 0, 0, 0);
        __syncthreads();
    }

    // C/D layout: col = lane&15, row = (lane>>4)*4 + reg  [m89/m91 verified]
    #pragma unroll
    for (int ni = 0; ni < 4; ++ni) {
        const int col = bn + wn * 64 + ni * 16 + m16;
        const float bi = bias[col], sc = scale[col], sh = shift[col];
        #pragma unroll
        for (int mi = 0; mi < 4; ++mi) {
            const int rbase = bm + wm * 64 + mi * 16 + kg * 4;
            #pragma unroll
            for (int r = 0; r < 4; ++r) {
                float val = (acc[mi][ni][r] + bi) * sc + sh;
                if (OUT_BF16)
                    ((u16*)outp)[(size_t)(rbase + r) * N + col] = f2bf(val);
                else
                    ((float*)outp)[(size_t)(rbase + r) * N + col] = val;
            }
        }
    }
}

// ---------------------------------------------------------------------------
// q_in = dwconv3x3_s2_SAME(x) + q_local_b + x[::2,::2]   (fp32 in, bf16 out)
// ---------------------------------------------------------------------------
__global__ __launch_bounds__(256)
void qin_kernel(const float* __restrict__ x, const float* __restrict__ w,
                const float* __restrict__ b, u16* __restrict__ qin)
{
    const int C4 = CIN / 4;   // 96
    int idx = blockIdx.x * 256 + threadIdx.x;
    if (idx >= BATCH * RES2 * RES2 * C4) return;
    int c4 = idx % C4;
    int r  = idx / C4;
    int j  = r % RES2; r /= RES2;
    int i  = r % RES2;
    int bb = r / RES2;

    const float4* x4 = (const float4*)x;
    const float4* w4 = (const float4*)w;
    float4 acc = make_float4(0.f, 0.f, 0.f, 0.f);
    #pragma unroll
    for (int dy = 0; dy < 3; ++dy) {
        int iy = 2 * i + dy;
        if (iy >= RES) continue;
        #pragma unroll
        for (int dx = 0; dx < 3; ++dx) {
            int ix = 2 * j + dx;
            if (ix >= RES) continue;
            float4 xv = x4[((size_t)(bb * RES + iy) * RES + ix) * C4 + c4];
            float4 wv = w4[(dy * 3 + dx) * C4 + c4];
            acc.x += xv.x * wv.x; acc.y += xv.y * wv.y;
            acc.z += xv.z * wv.z; acc.w += xv.w * wv.w;
        }
    }
    float4 bv = ((const float4*)b)[c4];
    float4 xs = x4[((size_t)(bb * RES + 2 * i) * RES + 2 * j) * C4 + c4];
    us4 o;
    o.x = f2bf(acc.x + bv.x + xs.x);
    o.y = f2bf(acc.y + bv.y + xs.y);
    o.z = f2bf(acc.z + bv.z + xs.z);
    o.w = f2bf(acc.w + bv.w + xs.w);
    ((us4*)qin)[idx] = o;
}

// ---------------------------------------------------------------------------
// v_local = BN(dwconv3x3_s2(v)) : v bf16 in, fp32 out
// ---------------------------------------------------------------------------
__global__ __launch_bounds__(256)
void vloc_kernel(const u16* __restrict__ v, const float* __restrict__ w,
                 const float* __restrict__ b, const float* __restrict__ s,
                 const float* __restrict__ sh, float* __restrict__ out)
{
    const int C4 = DHID / 4;   // 128
    int idx = blockIdx.x * 256 + threadIdx.x;
    if (idx >= BATCH * RES2 * RES2 * C4) return;
    int c4 = idx % C4;
    int r  = idx / C4;
    int j  = r % RES2; r /= RES2;
    int i  = r % RES2;
    int bb = r / RES2;

    const us4* v4 = (const us4*)v;
    const float4* w4 = (const float4*)w;
    float4 acc = make_float4(0.f, 0.f, 0.f, 0.f);
    #pragma unroll
    for (int dy = 0; dy < 3; ++dy) {
        int iy = 2 * i + dy;
        if (iy >= RES) continue;
        #pragma unroll
        for (int dx = 0; dx < 3; ++dx) {
            int ix = 2 * j + dx;
            if (ix >= RES) continue;
            us4 xu = v4[((size_t)(bb * RES + iy) * RES + ix) * C4 + c4];
            float4 wv = w4[(dy * 3 + dx) * C4 + c4];
            acc.x += bf2f(xu.x) * wv.x; acc.y += bf2f(xu.y) * wv.y;
            acc.z += bf2f(xu.z) * wv.z; acc.w += bf2f(xu.w) * wv.w;
        }
    }
    float4 bv = ((const float4*)b)[c4];
    float4 sv = ((const float4*)s)[c4];
    float4 hv = ((const float4*)sh)[c4];
    float4 o;
    o.x = (acc.x + bv.x) * sv.x + hv.x;
    o.y = (acc.y + bv.y) * sv.y + hv.y;
    o.z = (acc.z + bv.z) * sv.z + hv.z;
    o.w = (acc.w + bv.w) * sv.w + hv.w;
    ((float4*)out)[idx] = o;
}

// ---------------------------------------------------------------------------
// Split-K flash attention partials. Grid (b*h, split). Thread t<196 owns one
// query. q/k/v bf16; LDS tiles converted to fp32; online softmax in fp32.
// 13 key-tiles of 64 (last = 16 valid) split 5/4/4.
// Partials: pm/pl fp32, pacc bf16 (pre-normalization accumulator).
// ---------------------------------------------------------------------------
__constant__ int TSPLIT[4] = {0, 5, 9, 13};

__global__ __launch_bounds__(256)
void attn_split_kernel(const u16* __restrict__ q, const u16* __restrict__ k,
                       const u16* __restrict__ v, const float* __restrict__ bias,
                       float* __restrict__ pm, float* __restrict__ pl,
                       u16* __restrict__ pacc)
{
    __shared__ float ks[64][16];
    __shared__ float vs[64][64];
    __shared__ float bsm[NSEQ];

    const int t  = threadIdx.x;
    const int bh = blockIdx.x;
    const int s  = blockIdx.y;
    const int b  = bh >> 3;
    const int h  = bh & 7;

    for (int i = t; i < NSEQ; i += 256) bsm[i] = bias[h * NSEQ + i];

    float qr[16];
    float m = -1e30f, l = 0.f;
    float acc[64];
    #pragma unroll
    for (int d = 0; d < 64; ++d) acc[d] = 0.f;

    int pi = 0, pj = 0;
    if (t < N2SEQ) {
        pi = t / 14; pj = t % 14;
        const u16* qp = q + ((size_t)b * N2SEQ + t) * (NHEAD * KDIM) + h * KDIM;
        us8 q0 = *(const us8*)qp;
        us8 q1 = *(const us8*)(qp + 8);
        #pragma unroll
        for (int d = 0; d < 8; ++d) { qr[d] = bf2f(q0[d]); qr[d + 8] = bf2f(q1[d]); }
    }

    const float scl = 0.25f;   // KD^-0.5
    const int ts = TSPLIT[s], te = TSPLIT[s + 1];

    for (int ti = ts; ti < te; ++ti) {
        const int t0 = ti * 64;
        int nrows = NSEQ - t0; if (nrows > 64) nrows = 64;
        {   // K tile: 64x16 bf16 -> fp32
            int rr = t >> 2, cc = (t & 3) * 4;
            int gr = t0 + rr; if (gr >= NSEQ) gr = NSEQ - 1;
            us4 kv = *(const us4*)(k + ((size_t)b * NSEQ + gr) * (NHEAD * KDIM) + h * KDIM + cc);
            ks[rr][cc + 0] = bf2f(kv.x); ks[rr][cc + 1] = bf2f(kv.y);
            ks[rr][cc + 2] = bf2f(kv.z); ks[rr][cc + 3] = bf2f(kv.w);
        }
        #pragma unroll
        for (int it = 0; it < 2; ++it) {   // V tile: 64x64 bf16 -> fp32
            int idx = t + it * 256;
            int rr = idx >> 3, cc = (idx & 7) * 8;
            int gr = t0 + rr; if (gr >= NSEQ) gr = NSEQ - 1;
            us8 vv = *(const us8*)(v + ((size_t)b * NSEQ + gr) * DHID + h * DV + cc);
            #pragma unroll
            for (int d = 0; d < 8; ++d) vs[rr][cc + d] = bf2f(vv[d]);
        }
        __syncthreads();

        if (t < N2SEQ) {
            int ku = t0 / 28, kw = t0 % 28;
            for (int r = 0; r < nrows; ++r) {
                const float* kr = ks[r];
                float dot = 0.f;
                #pragma unroll
                for (int d = 0; d < 16; ++d) dot += qr[d] * kr[d];
                int d0 = 2 * pj - kw; if (d0 < 0) d0 = -d0;
                int d1 = 2 * pi - ku; if (d1 < 0) d1 = -d1;
                float lg = dot * scl + bsm[d0 * 28 + d1];
                if (lg > m) {
                    float al = __expf(m - lg);
                    m = lg;
                    l *= al;
                    #pragma unroll
                    for (int d = 0; d < 64; ++d) acc[d] *= al;
                }
                float p = __expf(lg - m);
                l += p;
                #pragma unroll
                for (int d4 = 0; d4 < 16; ++d4) {
                    float4 vv = *(const float4*)&vs[r][d4 * 4];
                    acc[d4 * 4 + 0] += p * vv.x;
                    acc[d4 * 4 + 1] += p * vv.y;
                    acc[d4 * 4 + 2] += p * vv.z;
                    acc[d4 * 4 + 3] += p * vv.w;
                }
                if (++kw == 28) { kw = 0; ++ku; }
            }
        }
        __syncthreads();
    }

    if (t < N2SEQ) {
        const size_t pidx = ((size_t)bh * 3 + s) * N2SEQ + t;
        pm[pidx] = m;
        pl[pidx] = l;
        u16* pa = pacc + pidx * 64;
        #pragma unroll
        for (int d4 = 0; d4 < 16; ++d4) {
            us4 r;
            r.x = f2bf(acc[d4 * 4 + 0]); r.y = f2bf(acc[d4 * 4 + 1]);
            r.z = f2bf(acc[d4 * 4 + 2]); r.w = f2bf(acc[d4 * 4 + 3]);
            ((us4*)pa)[d4] = r;
        }
    }
}

// ---------------------------------------------------------------------------
// Merge 3 splits, add v_local (fp32), emit bf16 input for the proj GEMM.
// One thread per (bh, q).
// ---------------------------------------------------------------------------
__global__ __launch_bounds__(256)
void attn_merge_kernel(const float* __restrict__ pm, const float* __restrict__ pl,
                       const u16* __restrict__ pacc, const float* __restrict__ vloc,
                       u16* __restrict__ outbf)
{
    int tid = blockIdx.x * 256 + threadIdx.x;
    if (tid >= BATCH * NHEAD * N2SEQ) return;
    int bh = tid / N2SEQ, qq = tid % N2SEQ;
    int b = bh >> 3, h = bh & 7;

    size_t p0 = ((size_t)bh * 3 + 0) * N2SEQ + qq;
    size_t p1 = p0 + N2SEQ, p2 = p1 + N2SEQ;
    float m0 = pm[p0], m1 = pm[p1], m2 = pm[p2];
    float M = fmaxf(m0, fmaxf(m1, m2));
    float w0 = __expf(m0 - M), w1 = __expf(m1 - M), w2 = __expf(m2 - M);
    float L = pl[p0] * w0 + pl[p1] * w1 + pl[p2] * w2;
    float inv = 1.0f / L;

    const us4* a0 = (const us4*)(pacc + p0 * 64);
    const us4* a1 = (const us4*)(pacc + p1 * 64);
    const us4* a2 = (const us4*)(pacc + p2 * 64);
    const float* vl = vloc + ((size_t)b * N2SEQ + qq) * DHID + h * DV;
    u16* ob = outbf + ((size_t)b * N2SEQ + qq) * DHID + h * DV;

    #pragma unroll
    for (int d4 = 0; d4 < 16; ++d4) {
        us4 x0 = a0[d4], x1 = a1[d4], x2 = a2[d4];
        float4 vv = *(const float4*)(vl + d4 * 4);
        us4 r;
        r.x = f2bf((bf2f(x0.x) * w0 + bf2f(x1.x) * w1 + bf2f(x2.x) * w2) * inv + vv.x);
        r.y = f2bf((bf2f(x0.y) * w0 + bf2f(x1.y) * w1 + bf2f(x2.y) * w2) * inv + vv.y);
        r.z = f2bf((bf2f(x0.z) * w0 + bf2f(x1.z) * w1 + bf2f(x2.z) * w2) * inv + vv.z);
        r.w = f2bf((bf2f(x0.w) * w0 + bf2f(x1.w) * w1 + bf2f(x2.w) * w2) * inv + vv.w);
        ((us4*)ob)[d4] = r;
    }
}

// ---------------------------------------------------------------------------
extern "C" void kernel_launch(void* const* d_in, const int* in_sizes, int n_in,
                              void* d_out, int out_size, void* d_ws, size_t ws_size,
                              hipStream_t stream)
{
    const float* x          = (const float*)d_in[0];
    const float* q_local_w  = (const float*)d_in[1];
    const float* q_local_b  = (const float*)d_in[2];
    const float* q_proj_w   = (const float*)d_in[3];
    const float* q_proj_b   = (const float*)d_in[4];
    const float* q_bn_s     = (const float*)d_in[5];
    const float* q_bn_b     = (const float*)d_in[6];
    const float* k_w        = (const float*)d_in[7];
    const float* k_b        = (const float*)d_in[8];
    const float* k_bn_s     = (const float*)d_in[9];
    const float* k_bn_b     = (const float*)d_in[10];
    const float* v_w        = (const float*)d_in[11];
    const float* v_b        = (const float*)d_in[12];
    const float* v_bn_s     = (const float*)d_in[13];
    const float* v_bn_b     = (const float*)d_in[14];
    const float* vloc_w     = (const float*)d_in[15];
    const float* vloc_b     = (const float*)d_in[16];
    const float* vloc_bn_s  = (const float*)d_in[17];
    const float* vloc_bn_b  = (const float*)d_in[18];
    const float* proj_w     = (const float*)d_in[19];
    const float* proj_b     = (const float*)d_in[20];
    const float* proj_bn_s  = (const float*)d_in[21];
    const float* proj_bn_b  = (const float*)d_in[22];
    const float* attn_bias  = (const float*)d_in[23];
    float* out = (float*)d_out;

    const int M1 = BATCH * NSEQ;    // 50176
    const int M2 = BATCH * N2SEQ;   // 12544

    // ---- workspace layout (bytes), total 155.5 MB (<160.6 MB proven) ----
    // Slot A (48,168,960 B) time-shared:
    //   phase 1-4: xb (38,535,168) + qin_bf (9,633,792)
    //   phase 6-7: pm (1,204,224) + pl (1,204,224) + pacc (38,535,168)
    char* p = (char*)d_ws;
    u16*   xb     = (u16*)p;
    u16*   qin_bf = (u16*)(p + 38535168);
    float* pm     = (float*)p;
    float* pl     = (float*)(p + 1204224);
    u16*   pacc   = (u16*)(p + 2408448);
    size_t off = 48168960;
    u16* kwt = (u16*)(p + off);                 // 384*128
    u16* vwt = kwt + (size_t)CIN * 128;         // 384*512
    u16* qwt = vwt + (size_t)CIN * DHID;        // 384*128
    u16* pwt = qwt + (size_t)CIN * 128;         // 512*768
    off += 1376256;
    u16* kbuf = (u16*)(p + off);   off += (size_t)M1 * 128 * 2;   // 12,845,056
    u16* vbuf = (u16*)(p + off);   off += (size_t)M1 * DHID * 2;  // 51,380,224
    u16* qbuf = (u16*)(p + off);   off += (size_t)M2 * 128 * 2;   //  3,211,264
    float* vloc = (float*)(p + off); off += (size_t)M2 * DHID * 4; // 25,690,112
    u16* vloc_bf = (u16*)(p + off);                                // 12,845,056

    // 1. casts
    {
        int n4 = M1 * CIN / 4;
        cast_bf16_kernel<<<dim3((n4 + 255) / 256), 256, 0, stream>>>(x, xb, n4);
    }
    castT_kernel<<<dim3((CIN * 128 + 255) / 256), 256, 0, stream>>>(k_w, kwt, CIN, 128);
    castT_kernel<<<dim3((CIN * DHID + 255) / 256), 256, 0, stream>>>(v_w, vwt, CIN, DHID);
    castT_kernel<<<dim3((CIN * 128 + 255) / 256), 256, 0, stream>>>(q_proj_w, qwt, CIN, 128);
    castT_kernel<<<dim3((DHID * 768 + 255) / 256), 256, 0, stream>>>(proj_w, pwt, DHID, 768);

    // 2. q_in (bf16)
    {
        int items = M2 * (CIN / 4);
        qin_kernel<<<dim3((items + 255) / 256), 256, 0, stream>>>(x, q_local_w, q_local_b, qin_bf);
    }
    // 3. k, v, q GEMMs (bf16 MFMA, bf16 out)
    gemm_mfma_kernel<1><<<dim3(M1 / TM, 128 / TN), 256, 0, stream>>>(
        xb, kwt, k_b, k_bn_s, k_bn_b, kbuf, M1, 128, CIN);
    gemm_mfma_kernel<1><<<dim3(M1 / TM, DHID / TN), 256, 0, stream>>>(
        xb, vwt, v_b, v_bn_s, v_bn_b, vbuf, M1, DHID, CIN);
    gemm_mfma_kernel<1><<<dim3(M2 / TM, 128 / TN), 256, 0, stream>>>(
        qin_bf, qwt, q_proj_b, q_bn_s, q_bn_b, qbuf, M2, 128, CIN);

    // 4. v_local (fp32)
    {
        int items = M2 * (DHID / 4);
        vloc_kernel<<<dim3((items + 255) / 256), 256, 0, stream>>>(
            vbuf, vloc_w, vloc_b, vloc_bn_s, vloc_bn_b, vloc);
    }
    // 5. split-K attention partials (overlays dead xb region)
    attn_split_kernel<<<dim3(BATCH * NHEAD, 3), 256, 0, stream>>>(
        qbuf, kbuf, vbuf, attn_bias, pm, pl, pacc);

    // 6. merge + add v_local -> bf16 proj input
    {
        int items = BATCH * NHEAD * N2SEQ;
        attn_merge_kernel<<<dim3((items + 255) / 256), 256, 0, stream>>>(
            pm, pl, pacc, vloc, vloc_bf);
    }
    // 7. proj GEMM (fp32 out)
    gemm_mfma_kernel<0><<<dim3(M2 / TM, 768 / TN), 256, 0, stream>>>(
        vloc_bf, pwt, proj_b, proj_bn_s, proj_bn_b, out, M2, 768, DHID);
}

// Round 4
// 450.949 us; speedup vs baseline: 2.4544x; 1.4758x over previous
//
#include <hip/hip_runtime.h>
#include <cstdint>

#define RES    28
#define RES2   14
#define NHEAD  8
#define KDIM   16
#define DV     64
#define DHID   512
#define NSEQ   784
#define N2SEQ  196
#define BATCH  64
#define CIN    384

typedef unsigned short u16;
typedef short  short4_t __attribute__((ext_vector_type(4)));
typedef short  short8_t __attribute__((ext_vector_type(8)));
typedef float  f32x4  __attribute__((ext_vector_type(4)));
typedef u16    us4    __attribute__((ext_vector_type(4)));
typedef u16    us8    __attribute__((ext_vector_type(8)));

__device__ __forceinline__ u16 f2bf(float f) {
    uint32_t u = __float_as_uint(f);
    return (u16)((u + 0x7fffu + ((u >> 16) & 1u)) >> 16);   // RNE
}
__device__ __forceinline__ float bf2f(u16 h) {
    return __uint_as_float(((uint32_t)h) << 16);
}

// ---------------------------------------------------------------------------
// fp32 -> bf16 cast, 4 elems/thread
// ---------------------------------------------------------------------------
__global__ __launch_bounds__(256)
void cast_bf16_kernel(const float* __restrict__ in, u16* __restrict__ out, int n4)
{
    int i = blockIdx.x * 256 + threadIdx.x;
    if (i >= n4) return;
    float4 v = ((const float4*)in)[i];
    us4 r;
    r.x = f2bf(v.x); r.y = f2bf(v.y); r.z = f2bf(v.z); r.w = f2bf(v.w);
    ((us4*)out)[i] = r;
}

// W[K,N] fp32 -> Wt[N,K] bf16
__global__ __launch_bounds__(256)
void castT_kernel(const float* __restrict__ W, u16* __restrict__ Wt, int K, int N)
{
    int i = blockIdx.x * 256 + threadIdx.x;
    if (i >= K * N) return;
    int n = i / K, k = i % K;
    Wt[i] = f2bf(W[(size_t)k * N + n]);
}

// ---------------------------------------------------------------------------
// MFMA GEMM (working round-3 version): out = epi(A[M,K] @ Bt[N,K]^T)
// ---------------------------------------------------------------------------
#define TM 128
#define TN 128
#define TK 32

template<int OUT_BF16>
__global__ __launch_bounds__(256)
void gemm_mfma_kernel(const u16* __restrict__ A, const u16* __restrict__ Bt,
                      const float* __restrict__ bias, const float* __restrict__ scale,
                      const float* __restrict__ shift, void* __restrict__ outp,
                      int M, int N, int K)
{
    __shared__ u16 As[TM * TK];
    __shared__ u16 Bs[TN * TK];

    const int t  = threadIdx.x;
    const int w  = t >> 6;
    const int li = t & 63;
    const int wm = w >> 1, wn = w & 1;
    const int bm = blockIdx.x * TM;
    const int bn = blockIdx.y * TN;
    const int m16 = li & 15;
    const int kg  = li >> 4;

    f32x4 acc[4][4];
    #pragma unroll
    for (int i = 0; i < 4; ++i)
        #pragma unroll
        for (int j = 0; j < 4; ++j) acc[i][j] = (f32x4)0.0f;

    for (int k0 = 0; k0 < K; k0 += TK) {
        #pragma unroll
        for (int i = 0; i < 2; ++i) {
            int c   = (w * 2 + i) * 64 + li;
            int row = c >> 2, kc = c & 3;
            const u16* ag = A  + (size_t)(bm + row) * K + k0 + kc * 8;
            const u16* bg = Bt + (size_t)(bn + row) * K + k0 + kc * 8;
            char* la = (char*)As + (size_t)(w * 2 + i) * 64 * 16;
            char* lb = (char*)Bs + (size_t)(w * 2 + i) * 64 * 16;
            __builtin_amdgcn_global_load_lds(
                (const __attribute__((address_space(1))) void*)ag,
                (__attribute__((address_space(3))) void*)la, 16, 0, 0);
            __builtin_amdgcn_global_load_lds(
                (const __attribute__((address_space(1))) void*)bg,
                (__attribute__((address_space(3))) void*)lb, 16, 0, 0);
        }
        __syncthreads();

        short8_t af[4], bf[4];
        #pragma unroll
        for (int mi = 0; mi < 4; ++mi)
            af[mi] = *(const short8_t*)&As[(wm * 64 + mi * 16 + m16) * TK + kg * 8];
        #pragma unroll
        for (int ni = 0; ni < 4; ++ni)
            bf[ni] = *(const short8_t*)&Bs[(wn * 64 + ni * 16 + m16) * TK + kg * 8];

        #pragma unroll
        for (int mi = 0; mi < 4; ++mi)
            #pragma unroll
            for (int ni = 0; ni < 4; ++ni)
                acc[mi][ni] = __builtin_amdgcn_mfma_f32_16x16x32_bf16(
                    af[mi], bf[ni], acc[mi][ni], 0, 0, 0);
        __syncthreads();
    }

    #pragma unroll
    for (int ni = 0; ni < 4; ++ni) {
        const int col = bn + wn * 64 + ni * 16 + m16;
        const float bi = bias[col], sc = scale[col], sh = shift[col];
        #pragma unroll
        for (int mi = 0; mi < 4; ++mi) {
            const int rbase = bm + wm * 64 + mi * 16 + kg * 4;
            #pragma unroll
            for (int r = 0; r < 4; ++r) {
                float val = (acc[mi][ni][r] + bi) * sc + sh;
                if (OUT_BF16)
                    ((u16*)outp)[(size_t)(rbase + r) * N + col] = f2bf(val);
                else
                    ((float*)outp)[(size_t)(rbase + r) * N + col] = val;
            }
        }
    }
}

// ---------------------------------------------------------------------------
// q_in = dwconv3x3_s2_SAME(x) + q_local_b + x[::2,::2]   (fp32 in, bf16 out)
// ---------------------------------------------------------------------------
__global__ __launch_bounds__(256)
void qin_kernel(const float* __restrict__ x, const float* __restrict__ w,
                const float* __restrict__ b, u16* __restrict__ qin)
{
    const int C4 = CIN / 4;
    int idx = blockIdx.x * 256 + threadIdx.x;
    if (idx >= BATCH * RES2 * RES2 * C4) return;
    int c4 = idx % C4;
    int r  = idx / C4;
    int j  = r % RES2; r /= RES2;
    int i  = r % RES2;
    int bb = r / RES2;

    const float4* x4 = (const float4*)x;
    const float4* w4 = (const float4*)w;
    float4 acc = make_float4(0.f, 0.f, 0.f, 0.f);
    #pragma unroll
    for (int dy = 0; dy < 3; ++dy) {
        int iy = 2 * i + dy;
        if (iy >= RES) continue;
        #pragma unroll
        for (int dx = 0; dx < 3; ++dx) {
            int ix = 2 * j + dx;
            if (ix >= RES) continue;
            float4 xv = x4[((size_t)(bb * RES + iy) * RES + ix) * C4 + c4];
            float4 wv = w4[(dy * 3 + dx) * C4 + c4];
            acc.x += xv.x * wv.x; acc.y += xv.y * wv.y;
            acc.z += xv.z * wv.z; acc.w += xv.w * wv.w;
        }
    }
    float4 bv = ((const float4*)b)[c4];
    float4 xs = x4[((size_t)(bb * RES + 2 * i) * RES + 2 * j) * C4 + c4];
    us4 o;
    o.x = f2bf(acc.x + bv.x + xs.x);
    o.y = f2bf(acc.y + bv.y + xs.y);
    o.z = f2bf(acc.z + bv.z + xs.z);
    o.w = f2bf(acc.w + bv.w + xs.w);
    ((us4*)qin)[idx] = o;
}

// ---------------------------------------------------------------------------
// v_local = BN(dwconv3x3_s2(v)) : v bf16 in, bf16 out (attention RMWs this)
// ---------------------------------------------------------------------------
__global__ __launch_bounds__(256)
void vloc_kernel(const u16* __restrict__ v, const float* __restrict__ w,
                 const float* __restrict__ b, const float* __restrict__ s,
                 const float* __restrict__ sh, u16* __restrict__ out)
{
    const int C4 = DHID / 4;
    int idx = blockIdx.x * 256 + threadIdx.x;
    if (idx >= BATCH * RES2 * RES2 * C4) return;
    int c4 = idx % C4;
    int r  = idx / C4;
    int j  = r % RES2; r /= RES2;
    int i  = r % RES2;
    int bb = r / RES2;

    const us4* v4 = (const us4*)v;
    const float4* w4 = (const float4*)w;
    float4 acc = make_float4(0.f, 0.f, 0.f, 0.f);
    #pragma unroll
    for (int dy = 0; dy < 3; ++dy) {
        int iy = 2 * i + dy;
        if (iy >= RES) continue;
        #pragma unroll
        for (int dx = 0; dx < 3; ++dx) {
            int ix = 2 * j + dx;
            if (ix >= RES) continue;
            us4 xu = v4[((size_t)(bb * RES + iy) * RES + ix) * C4 + c4];
            float4 wv = w4[(dy * 3 + dx) * C4 + c4];
            acc.x += bf2f(xu.x) * wv.x; acc.y += bf2f(xu.y) * wv.y;
            acc.z += bf2f(xu.z) * wv.z; acc.w += bf2f(xu.w) * wv.w;
        }
    }
    float4 bv = ((const float4*)b)[c4];
    float4 sv = ((const float4*)s)[c4];
    float4 hv = ((const float4*)sh)[c4];
    us4 o;
    o.x = f2bf((acc.x + bv.x) * sv.x + hv.x);
    o.y = f2bf((acc.y + bv.y) * sv.y + hv.y);
    o.z = f2bf((acc.z + bv.z) * sv.z + hv.z);
    o.w = f2bf((acc.w + bv.w) * sv.w + hv.w);
    ((us4*)out)[idx] = o;
}

// ---------------------------------------------------------------------------
// V transpose: vbuf[b][token(784)][512] -> vt[b][h][d(64)][token(784)]
// Block: 64 keys x 64 channels tile via LDS. Grid (b, keytile 13, h 8).
// ---------------------------------------------------------------------------
__global__ __launch_bounds__(256)
void vt_transpose_kernel(const u16* __restrict__ vbuf, u16* __restrict__ vt)
{
    __shared__ u16 tile[64][66];
    const int t  = threadIdx.x;
    const int b  = blockIdx.x;
    const int k0 = blockIdx.y * 64;
    const int h  = blockIdx.z;

    {   // coalesced read: 64 key-rows x 64 ch
        int kr = t >> 2, cc = (t & 3) * 16;
        int key = k0 + kr;
        if (key < NSEQ) {
            const u16* src = vbuf + ((size_t)b * NSEQ + key) * DHID + h * 64 + cc;
            us8 v0 = *(const us8*)src;
            us8 v1 = *(const us8*)(src + 8);
            #pragma unroll
            for (int i = 0; i < 8; ++i) { tile[kr][cc + i] = v0[i]; tile[kr][cc + 8 + i] = v1[i]; }
        }
    }
    __syncthreads();
    {   // coalesced write: 64 ch-rows x 64 keys
        int cr = t >> 2, kc = (t & 3) * 16;
        if (k0 + kc < NSEQ) {
            us8 o0, o1;
            #pragma unroll
            for (int i = 0; i < 8; ++i) { o0[i] = tile[kc + i][cr]; o1[i] = tile[kc + 8 + i][cr]; }
            u16* dst = vt + (((size_t)b * NHEAD + h) * 64 + cr) * NSEQ + k0 + kc;
            *(us8*)dst = o0;
            *(us8*)(dst + 8) = o1;
        }
    }
}

// ---------------------------------------------------------------------------
// biasT[h][key][q] (fp32) = attn_bias[h][ |2pj-kw|*28 + |2pi-ku| ]
// ---------------------------------------------------------------------------
__global__ __launch_bounds__(256)
void biasT_kernel(const float* __restrict__ bias, float* __restrict__ biasT)
{
    int tid = blockIdx.x * 256 + threadIdx.x;
    if (tid >= NHEAD * NSEQ * N2SEQ) return;
    int q   = tid % N2SEQ;
    int rem = tid / N2SEQ;
    int key = rem % NSEQ;
    int h   = rem / NSEQ;
    int pi = q / 14, pj = q % 14;
    int ku = key / 28, kw = key % 28;
    int d0 = 2 * pj - kw; if (d0 < 0) d0 = -d0;
    int d1 = 2 * pi - ku; if (d1 < 0) d1 = -d1;
    biasT[tid] = bias[h * NSEQ + d0 * 28 + d1];
}

// ---------------------------------------------------------------------------
// MFMA flash attention.
// Grid (bh=512, qg=7), 128 threads = 2 waves; wave w owns Q-tile qg*2+w (16 q).
// S^T = K·Q^T via mfma(16x16x32, zero-padded K-dim): C-layout of S^T
// (col=q=lane&15, row=key=quad*4+reg) IS the A-layout for P·V.
// PV k-permutation: mfma k = quad*8 + f*4 + r  <->  key = f*16 + quad*4 + r,
// applied to both P-pack and Vt B-frag reads (dot product perm-invariant).
// Output: io (vloc_bf) += P·V / l  (read-modify-write, bf16).
// ---------------------------------------------------------------------------
__global__ __launch_bounds__(128)
void attn_mfma_kernel(const u16* __restrict__ q, const u16* __restrict__ k,
                      const u16* __restrict__ vt, const float* __restrict__ biasT,
                      u16* __restrict__ io)
{
    __shared__ u16 Ks[64 * 16];        // [key][kd], 32B rows (global_load_lds)
    __shared__ u16 Vs[64 * 68];        // [d][key] stride 68 (bank spread)

    const int t    = threadIdx.x;
    const int w    = t >> 6;
    const int lane = t & 63;
    const int col  = lane & 15;        // q within tile / d within nsub
    const int quad = lane >> 4;
    const int bh = blockIdx.x;
    const int b  = bh >> 3;
    const int h  = bh & 7;
    const int qtile = blockIdx.y * 2 + w;
    const bool qvalid = qtile * 16 < N2SEQ;
    const int qbase = qvalid ? qtile * 16 : 192;

    // Q B-frag (n=q=lane&15, kd=quad*8+j; quads 2,3 are K-dim zero padding)
    int qq = qbase + col; if (qq > 195) qq = 195;
    short8_t qf = (short8_t)0;
    if (quad < 2)
        qf = *(const short8_t*)(q + ((size_t)(b * N2SEQ + qq) * 128) + h * 16 + quad * 8);

    f32x4 O[4];
    #pragma unroll
    for (int i = 0; i < 4; ++i) O[i] = (f32x4)0.0f;
    float m = -3e38f, l = 0.f;

    const u16* vtb = vt + (size_t)bh * 64 * NSEQ;

    for (int ti = 0; ti < 13; ++ti) {
        const int t0 = ti * 64;
        {   // K stage: 128 chunks of 16B via global_load_lds
            int c = w * 64 + lane;
            int row = c >> 1;
            int tok = t0 + row; if (tok > 783) tok = 783;
            const u16* src = k + ((size_t)(b * NSEQ + tok) * 128) + h * 16 + (c & 1) * 8;
            char* dst = (char*)Ks + w * 1024;
            __builtin_amdgcn_global_load_lds(
                (const __attribute__((address_space(1))) void*)src,
                (__attribute__((address_space(3))) void*)dst, 16, 0, 0);
        }
        {   // V stage: thread t loads 32 keys of channel d = t>>1
            int d = t >> 1, pr = t & 1;
            const u16* src = vtb + (size_t)d * NSEQ;
            u16* dst = Vs + d * 68 + pr * 32;
            #pragma unroll
            for (int i = 0; i < 4; ++i) {
                int kk = t0 + pr * 32 + i * 8; if (kk > 776) kk = 776;
                us8 vv = *(const us8*)(src + kk);
                us4 lo, hi;
                lo.x = vv[0]; lo.y = vv[1]; lo.z = vv[2]; lo.w = vv[3];
                hi.x = vv[4]; hi.y = vv[5]; hi.z = vv[6]; hi.w = vv[7];
                *(us4*)(dst + i * 8)     = lo;
                *(us4*)(dst + i * 8 + 4) = hi;
            }
        }
        __syncthreads();

        // S^T = K·Q^T : 4 mfma (one per 16-key subtile)
        f32x4 S[4];
        #pragma unroll
        for (int ks = 0; ks < 4; ++ks) {
            short8_t kf = (short8_t)0;
            if (quad < 2)
                kf = *(const short8_t*)&Ks[(ks * 16 + col) * 16 + quad * 8];
            S[ks] = __builtin_amdgcn_mfma_f32_16x16x32_bf16(kf, qf, (f32x4)0.0f, 0, 0, 0);
        }

        // logits = S*scale + biasT, mask phantom keys
        float p[16];
        float mt = -3e38f;
        #pragma unroll
        for (int ks = 0; ks < 4; ++ks) {
            #pragma unroll
            for (int r = 0; r < 4; ++r) {
                int key = t0 + ks * 16 + quad * 4 + r;
                float lg;
                if (key < NSEQ)
                    lg = S[ks][r] * 0.25f + biasT[((size_t)h * NSEQ + key) * N2SEQ + qbase + col];
                else
                    lg = -1e30f;
                p[ks * 4 + r] = lg;
                mt = fmaxf(mt, lg);
            }
        }
        // column(q)-wise max across the 4 quads (lanes lane^16, lane^32)
        mt = fmaxf(mt, __shfl_xor(mt, 16));
        mt = fmaxf(mt, __shfl_xor(mt, 32));
        float mnew = fmaxf(m, mt);
        float alpha = __expf(m - mnew);
        m = mnew;
        float s = 0.f;
        #pragma unroll
        for (int i = 0; i < 16; ++i) { p[i] = __expf(p[i] - mnew); s += p[i]; }
        s += __shfl_xor(s, 16);
        s += __shfl_xor(s, 32);
        l = l * alpha + s;

        // rescale O: alpha per output-row q' = quad*4+r (fetch from lane q')
        float ar[4];
        #pragma unroll
        for (int r = 0; r < 4; ++r) ar[r] = __shfl(alpha, quad * 4 + r);
        #pragma unroll
        for (int ns = 0; ns < 4; ++ns)
            #pragma unroll
            for (int r = 0; r < 4; ++r) O[ns][r] *= ar[r];

        // pack P to bf16 A-frags: pf[pr][j=f*4+r] = p[(2pr+f)*4 + r]
        short8_t pf[2];
        #pragma unroll
        for (int pr = 0; pr < 2; ++pr)
            #pragma unroll
            for (int j = 0; j < 8; ++j)
                pf[pr][j] = (short)f2bf(p[(2 * pr + (j >> 2)) * 4 + (j & 3)]);

        // PV: O[ns] += P · V  (B-frag from Vs with matching k-permutation)
        #pragma unroll
        for (int ns = 0; ns < 4; ++ns) {
            #pragma unroll
            for (int pr = 0; pr < 2; ++pr) {
                const u16* vrow = &Vs[(ns * 16 + col) * 68 + pr * 32 + quad * 4];
                us4 v0 = *(const us4*)vrow;
                us4 v1 = *(const us4*)(vrow + 16);
                short8_t vf;
                vf[0] = (short)v0.x; vf[1] = (short)v0.y; vf[2] = (short)v0.z; vf[3] = (short)v0.w;
                vf[4] = (short)v1.x; vf[5] = (short)v1.y; vf[6] = (short)v1.z; vf[7] = (short)v1.w;
                O[ns] = __builtin_amdgcn_mfma_f32_16x16x32_bf16(pf[pr], vf, O[ns], 0, 0, 0);
            }
        }
        __syncthreads();
    }

    // epilogue: O/l + v_local, RMW io
    float linv = 1.0f / l;
    float lr[4];
    #pragma unroll
    for (int r = 0; r < 4; ++r) lr[r] = __shfl(linv, quad * 4 + r);

    if (qvalid) {
        #pragma unroll
        for (int ns = 0; ns < 4; ++ns) {
            #pragma unroll
            for (int r = 0; r < 4; ++r) {
                int qg2 = qbase + quad * 4 + r;
                if (qg2 < N2SEQ) {
                    size_t a = ((size_t)(b * N2SEQ + qg2) * DHID) + h * 64 + ns * 16 + col;
                    io[a] = f2bf(O[ns][r] * lr[r] + bf2f(io[a]));
                }
            }
        }
    }
}

// ---------------------------------------------------------------------------
extern "C" void kernel_launch(void* const* d_in, const int* in_sizes, int n_in,
                              void* d_out, int out_size, void* d_ws, size_t ws_size,
                              hipStream_t stream)
{
    const float* x          = (const float*)d_in[0];
    const float* q_local_w  = (const float*)d_in[1];
    const float* q_local_b  = (const float*)d_in[2];
    const float* q_proj_w   = (const float*)d_in[3];
    const float* q_proj_b   = (const float*)d_in[4];
    const float* q_bn_s     = (const float*)d_in[5];
    const float* q_bn_b     = (const float*)d_in[6];
    const float* k_w        = (const float*)d_in[7];
    const float* k_b        = (const float*)d_in[8];
    const float* k_bn_s     = (const float*)d_in[9];
    const float* k_bn_b     = (const float*)d_in[10];
    const float* v_w        = (const float*)d_in[11];
    const float* v_b        = (const float*)d_in[12];
    const float* v_bn_s     = (const float*)d_in[13];
    const float* v_bn_b     = (const float*)d_in[14];
    const float* vloc_w     = (const float*)d_in[15];
    const float* vloc_b     = (const float*)d_in[16];
    const float* vloc_bn_s  = (const float*)d_in[17];
    const float* vloc_bn_b  = (const float*)d_in[18];
    const float* proj_w     = (const float*)d_in[19];
    const float* proj_b     = (const float*)d_in[20];
    const float* proj_bn_s  = (const float*)d_in[21];
    const float* proj_bn_b  = (const float*)d_in[22];
    const float* attn_bias  = (const float*)d_in[23];
    float* out = (float*)d_out;

    const int M1 = BATCH * NSEQ;    // 50176
    const int M2 = BATCH * N2SEQ;   // 12544

    // ---- workspace (bytes), total ~138 MB ----
    // Region A (51,380,224) time-shared: [xb 38,535,168 | qin_bf 9,633,792]
    // during phases 1-4, then vt[b][h][64][784] bf16 after the QKV GEMMs.
    char* p = (char*)d_ws;
    u16* xb     = (u16*)p;
    u16* qin_bf = (u16*)(p + 38535168);
    u16* vt     = (u16*)p;
    size_t off = 51380224;
    u16* kwt = (u16*)(p + off);
    u16* vwt = kwt + (size_t)CIN * 128;
    u16* qwt = vwt + (size_t)CIN * DHID;
    u16* pwt = qwt + (size_t)CIN * 128;
    off += 1376256;
    u16* kbuf = (u16*)(p + off);    off += (size_t)M1 * 128 * 2;
    u16* vbuf = (u16*)(p + off);    off += (size_t)M1 * DHID * 2;
    u16* qbuf = (u16*)(p + off);    off += (size_t)M2 * 128 * 2;
    u16* vloc_bf = (u16*)(p + off); off += (size_t)M2 * DHID * 2;
    float* biasT = (float*)(p + off);   // 8*784*196*4 = 4,917,248

    // 1. casts
    {
        int n4 = M1 * CIN / 4;
        cast_bf16_kernel<<<dim3((n4 + 255) / 256), 256, 0, stream>>>(x, xb, n4);
    }
    castT_kernel<<<dim3((CIN * 128 + 255) / 256), 256, 0, stream>>>(k_w, kwt, CIN, 128);
    castT_kernel<<<dim3((CIN * DHID + 255) / 256), 256, 0, stream>>>(v_w, vwt, CIN, DHID);
    castT_kernel<<<dim3((CIN * 128 + 255) / 256), 256, 0, stream>>>(q_proj_w, qwt, CIN, 128);
    castT_kernel<<<dim3((DHID * 768 + 255) / 256), 256, 0, stream>>>(proj_w, pwt, DHID, 768);
    biasT_kernel<<<dim3((NHEAD * NSEQ * N2SEQ + 255) / 256), 256, 0, stream>>>(attn_bias, biasT);

    // 2. q_in (bf16)
    {
        int items = M2 * (CIN / 4);
        qin_kernel<<<dim3((items + 255) / 256), 256, 0, stream>>>(x, q_local_w, q_local_b, qin_bf);
    }
    // 3. k, v, q GEMMs
    gemm_mfma_kernel<1><<<dim3(M1 / TM, 128 / TN), 256, 0, stream>>>(
        xb, kwt, k_b, k_bn_s, k_bn_b, kbuf, M1, 128, CIN);
    gemm_mfma_kernel<1><<<dim3(M1 / TM, DHID / TN), 256, 0, stream>>>(
        xb, vwt, v_b, v_bn_s, v_bn_b, vbuf, M1, DHID, CIN);
    gemm_mfma_kernel<1><<<dim3(M2 / TM, 128 / TN), 256, 0, stream>>>(
        qin_bf, qwt, q_proj_b, q_bn_s, q_bn_b, qbuf, M2, 128, CIN);

    // 4. V transpose (overwrites region A — xb/qin_bf now dead)
    vt_transpose_kernel<<<dim3(BATCH, 13, NHEAD), 256, 0, stream>>>(vbuf, vt);

    // 5. v_local (bf16 — attention adds into it)
    {
        int items = M2 * (DHID / 4);
        vloc_kernel<<<dim3((items + 255) / 256), 256, 0, stream>>>(
            vbuf, vloc_w, vloc_b, vloc_bn_s, vloc_bn_b, vloc_bf);
    }
    // 6. MFMA flash attention (RMW vloc_bf)
    attn_mfma_kernel<<<dim3(BATCH * NHEAD, 7), 128, 0, stream>>>(
        qbuf, kbuf, vt, biasT, vloc_bf);

    // 7. proj GEMM (fp32 out)
    gemm_mfma_kernel<0><<<dim3(M2 / TM, 768 / TN), 256, 0, stream>>>(
        vloc_bf, pwt, proj_b, proj_bn_s, proj_bn_b, out, M2, 768, DHID);
}

// Round 5
// 423.098 us; speedup vs baseline: 2.6160x; 1.0658x over previous
//
#include <hip/hip_runtime.h>
#include <cstdint>

#define RES    28
#define RES2   14
#define NHEAD  8
#define KDIM   16
#define DV     64
#define DHID   512
#define NSEQ   784
#define N2SEQ  196
#define BATCH  64
#define CIN    384

typedef unsigned short u16;
typedef short  short8_t __attribute__((ext_vector_type(8)));
typedef float  f32x4  __attribute__((ext_vector_type(4)));
typedef u16    us4    __attribute__((ext_vector_type(4)));
typedef u16    us8    __attribute__((ext_vector_type(8)));

__device__ __forceinline__ u16 f2bf(float f) {
    uint32_t u = __float_as_uint(f);
    return (u16)((u + 0x7fffu + ((u >> 16) & 1u)) >> 16);   // RNE
}
__device__ __forceinline__ float bf2f(u16 h) {
    return __uint_as_float(((uint32_t)h) << 16);
}

// ---------------------------------------------------------------------------
// fp32 -> bf16 cast, 4 elems/thread
// ---------------------------------------------------------------------------
__global__ __launch_bounds__(256)
void cast_bf16_kernel(const float* __restrict__ in, u16* __restrict__ out, int n4)
{
    int i = blockIdx.x * 256 + threadIdx.x;
    if (i >= n4) return;
    float4 v = ((const float4*)in)[i];
    us4 r;
    r.x = f2bf(v.x); r.y = f2bf(v.y); r.z = f2bf(v.z); r.w = f2bf(v.w);
    ((us4*)out)[i] = r;
}

// W[K,N] fp32 -> Wt[N,K] bf16
__global__ __launch_bounds__(256)
void castT_kernel(const float* __restrict__ W, u16* __restrict__ Wt, int K, int N)
{
    int i = blockIdx.x * 256 + threadIdx.x;
    if (i >= K * N) return;
    int n = i / K, k = i % K;
    Wt[i] = f2bf(W[(size_t)k * N + n]);
}

// fold softmax scale 0.25 into q GEMM epilogue vectors
__global__ void scale_qsb_kernel(const float* __restrict__ s, const float* __restrict__ b,
                                 float* __restrict__ o)
{
    int i = threadIdx.x;   // 128
    o[i] = 0.25f * s[i];
    o[128 + i] = 0.25f * b[i];
}

// ---------------------------------------------------------------------------
// biasC: attention bias pre-arranged in MFMA C-fragment layout
// linear idx = (((h*13+ti)*4+ks)*13+qt)*64 + lane, value = f32x4 over r.
// key = ti*64+ks*16+quad*4+r, q = qt*16+col; invalid key/q -> -1e30 (mask).
// ---------------------------------------------------------------------------
__global__ __launch_bounds__(256)
void biasC_kernel(const float* __restrict__ bias, float* __restrict__ biasC)
{
    int tid = blockIdx.x * 256 + threadIdx.x;
    if (tid >= NHEAD * 13 * 4 * 13 * 64) return;
    int lane = tid & 63;
    int rem  = tid >> 6;
    int qt = rem % 13; rem /= 13;
    int ks = rem % 4;  rem /= 4;
    int ti = rem % 13;
    int h  = rem / 13;
    int col = lane & 15, quad = lane >> 4;
    int q = qt * 16 + col;
    float4 out;
    float* po = &out.x;
    #pragma unroll
    for (int r = 0; r < 4; ++r) {
        int key = ti * 64 + ks * 16 + quad * 4 + r;
        float v;
        if (key >= NSEQ || q >= N2SEQ) {
            v = -1e30f;
        } else {
            int pi = q / 14, pj = q % 14;
            int ku = key / 28, kw = key % 28;
            int d0 = 2 * pj - kw; if (d0 < 0) d0 = -d0;
            int d1 = 2 * pi - ku; if (d1 < 0) d1 = -d1;
            v = bias[h * NSEQ + d0 * 28 + d1];
        }
        po[r] = v;
    }
    ((float4*)biasC)[tid] = out;
}

// ---------------------------------------------------------------------------
// MFMA GEMM: out = epi(A[M,K] @ Bt[N,K]^T)
// OUT_MODE: 0 = fp32 flat [M][N]; 1 = bf16 flat; 2 = bf16 head-split:
//   col -> h=col>>4, row -> (b=row/rpb, tok=row%rpb); out[((b*8+h)*rpb+tok)*16 + col&15]
// ---------------------------------------------------------------------------
#define TM 128
#define TN 128
#define TK 32

template<int OUT_MODE>
__global__ __launch_bounds__(256)
void gemm_mfma_kernel(const u16* __restrict__ A, const u16* __restrict__ Bt,
                      const float* __restrict__ bias, const float* __restrict__ scale,
                      const float* __restrict__ shift, void* __restrict__ outp,
                      int M, int N, int K, int rpb)
{
    __shared__ u16 As[TM * TK];
    __shared__ u16 Bs[TN * TK];

    const int t  = threadIdx.x;
    const int w  = t >> 6;
    const int li = t & 63;
    const int wm = w >> 1, wn = w & 1;
    const int bm = blockIdx.x * TM;
    const int bn = blockIdx.y * TN;
    const int m16 = li & 15;
    const int kg  = li >> 4;

    f32x4 acc[4][4];
    #pragma unroll
    for (int i = 0; i < 4; ++i)
        #pragma unroll
        for (int j = 0; j < 4; ++j) acc[i][j] = (f32x4)0.0f;

    for (int k0 = 0; k0 < K; k0 += TK) {
        #pragma unroll
        for (int i = 0; i < 2; ++i) {
            int c   = (w * 2 + i) * 64 + li;
            int row = c >> 2, kc = c & 3;
            const u16* ag = A  + (size_t)(bm + row) * K + k0 + kc * 8;
            const u16* bg = Bt + (size_t)(bn + row) * K + k0 + kc * 8;
            char* la = (char*)As + (size_t)(w * 2 + i) * 64 * 16;
            char* lb = (char*)Bs + (size_t)(w * 2 + i) * 64 * 16;
            __builtin_amdgcn_global_load_lds(
                (const __attribute__((address_space(1))) void*)ag,
                (__attribute__((address_space(3))) void*)la, 16, 0, 0);
            __builtin_amdgcn_global_load_lds(
                (const __attribute__((address_space(1))) void*)bg,
                (__attribute__((address_space(3))) void*)lb, 16, 0, 0);
        }
        __syncthreads();

        short8_t af[4], bf[4];
        #pragma unroll
        for (int mi = 0; mi < 4; ++mi)
            af[mi] = *(const short8_t*)&As[(wm * 64 + mi * 16 + m16) * TK + kg * 8];
        #pragma unroll
        for (int ni = 0; ni < 4; ++ni)
            bf[ni] = *(const short8_t*)&Bs[(wn * 64 + ni * 16 + m16) * TK + kg * 8];

        #pragma unroll
        for (int mi = 0; mi < 4; ++mi)
            #pragma unroll
            for (int ni = 0; ni < 4; ++ni)
                acc[mi][ni] = __builtin_amdgcn_mfma_f32_16x16x32_bf16(
                    af[mi], bf[ni], acc[mi][ni], 0, 0, 0);
        __syncthreads();
    }

    #pragma unroll
    for (int ni = 0; ni < 4; ++ni) {
        const int col = bn + wn * 64 + ni * 16 + m16;
        const float bi = bias[col], sc = scale[col], sh = shift[col];
        #pragma unroll
        for (int mi = 0; mi < 4; ++mi) {
            const int rbase = bm + wm * 64 + mi * 16 + kg * 4;
            #pragma unroll
            for (int r = 0; r < 4; ++r) {
                float val = (acc[mi][ni][r] + bi) * sc + sh;
                const int row = rbase + r;
                if (OUT_MODE == 0) {
                    ((float*)outp)[(size_t)row * N + col] = val;
                } else if (OUT_MODE == 1) {
                    ((u16*)outp)[(size_t)row * N + col] = f2bf(val);
                } else {
                    int bb = row / rpb, tok = row % rpb;
                    int hh = col >> 4;
                    ((u16*)outp)[((size_t)(bb * NHEAD + hh) * rpb + tok) * 16 + (col & 15)] = f2bf(val);
                }
            }
        }
    }
}

// ---------------------------------------------------------------------------
// q_in = dwconv3x3_s2_SAME(x) + q_local_b + x[::2,::2]   (fp32 in, bf16 out)
// ---------------------------------------------------------------------------
__global__ __launch_bounds__(256)
void qin_kernel(const float* __restrict__ x, const float* __restrict__ w,
                const float* __restrict__ b, u16* __restrict__ qin)
{
    const int C4 = CIN / 4;
    int idx = blockIdx.x * 256 + threadIdx.x;
    if (idx >= BATCH * RES2 * RES2 * C4) return;
    int c4 = idx % C4;
    int r  = idx / C4;
    int j  = r % RES2; r /= RES2;
    int i  = r % RES2;
    int bb = r / RES2;

    const float4* x4 = (const float4*)x;
    const float4* w4 = (const float4*)w;
    float4 acc = make_float4(0.f, 0.f, 0.f, 0.f);
    #pragma unroll
    for (int dy = 0; dy < 3; ++dy) {
        int iy = 2 * i + dy;
        if (iy >= RES) continue;
        #pragma unroll
        for (int dx = 0; dx < 3; ++dx) {
            int ix = 2 * j + dx;
            if (ix >= RES) continue;
            float4 xv = x4[((size_t)(bb * RES + iy) * RES + ix) * C4 + c4];
            float4 wv = w4[(dy * 3 + dx) * C4 + c4];
            acc.x += xv.x * wv.x; acc.y += xv.y * wv.y;
            acc.z += xv.z * wv.z; acc.w += xv.w * wv.w;
        }
    }
    float4 bv = ((const float4*)b)[c4];
    float4 xs = x4[((size_t)(bb * RES + 2 * i) * RES + 2 * j) * C4 + c4];
    us4 o;
    o.x = f2bf(acc.x + bv.x + xs.x);
    o.y = f2bf(acc.y + bv.y + xs.y);
    o.z = f2bf(acc.z + bv.z + xs.z);
    o.w = f2bf(acc.w + bv.w + xs.w);
    ((us4*)qin)[idx] = o;
}

// ---------------------------------------------------------------------------
// v_local = BN(dwconv3x3_s2(v)) : v bf16 in, bf16 out (attention RMWs this)
// ---------------------------------------------------------------------------
__global__ __launch_bounds__(256)
void vloc_kernel(const u16* __restrict__ v, const float* __restrict__ w,
                 const float* __restrict__ b, const float* __restrict__ s,
                 const float* __restrict__ sh, u16* __restrict__ out)
{
    const int C4 = DHID / 4;
    int idx = blockIdx.x * 256 + threadIdx.x;
    if (idx >= BATCH * RES2 * RES2 * C4) return;
    int c4 = idx % C4;
    int r  = idx / C4;
    int j  = r % RES2; r /= RES2;
    int i  = r % RES2;
    int bb = r / RES2;

    const us4* v4 = (const us4*)v;
    const float4* w4 = (const float4*)w;
    float4 acc = make_float4(0.f, 0.f, 0.f, 0.f);
    #pragma unroll
    for (int dy = 0; dy < 3; ++dy) {
        int iy = 2 * i + dy;
        if (iy >= RES) continue;
        #pragma unroll
        for (int dx = 0; dx < 3; ++dx) {
            int ix = 2 * j + dx;
            if (ix >= RES) continue;
            us4 xu = v4[((size_t)(bb * RES + iy) * RES + ix) * C4 + c4];
            float4 wv = w4[(dy * 3 + dx) * C4 + c4];
            acc.x += bf2f(xu.x) * wv.x; acc.y += bf2f(xu.y) * wv.y;
            acc.z += bf2f(xu.z) * wv.z; acc.w += bf2f(xu.w) * wv.w;
        }
    }
    float4 bv = ((const float4*)b)[c4];
    float4 sv = ((const float4*)s)[c4];
    float4 hv = ((const float4*)sh)[c4];
    us4 o;
    o.x = f2bf((acc.x + bv.x) * sv.x + hv.x);
    o.y = f2bf((acc.y + bv.y) * sv.y + hv.y);
    o.z = f2bf((acc.z + bv.z) * sv.z + hv.z);
    o.w = f2bf((acc.w + bv.w) * sv.w + hv.w);
    ((us4*)out)[idx] = o;
}

// ---------------------------------------------------------------------------
// V transpose: vbuf[b][token(784)][512] -> vt[b][h][d(64)][token(784)]
// ---------------------------------------------------------------------------
__global__ __launch_bounds__(256)
void vt_transpose_kernel(const u16* __restrict__ vbuf, u16* __restrict__ vt)
{
    __shared__ u16 tile[64][66];
    const int t  = threadIdx.x;
    const int b  = blockIdx.x;
    const int k0 = blockIdx.y * 64;
    const int h  = blockIdx.z;

    {   // coalesced read: 64 key-rows x 64 ch
        int kr = t >> 2, cc = (t & 3) * 16;
        int key = k0 + kr;
        if (key < NSEQ) {
            const u16* src = vbuf + ((size_t)b * NSEQ + key) * DHID + h * 64 + cc;
            us8 v0 = *(const us8*)src;
            us8 v1 = *(const us8*)(src + 8);
            #pragma unroll
            for (int i = 0; i < 8; ++i) { tile[kr][cc + i] = v0[i]; tile[kr][cc + 8 + i] = v1[i]; }
        }
    }
    __syncthreads();
    {   // coalesced write: 64 ch-rows x 64 keys
        int cr = t >> 2, kc = (t & 3) * 16;
        if (k0 + kc < NSEQ) {
            us8 o0, o1;
            #pragma unroll
            for (int i = 0; i < 8; ++i) { o0[i] = tile[kc + i][cr]; o1[i] = tile[kc + 8 + i][cr]; }
            u16* dst = vt + (((size_t)b * NHEAD + h) * 64 + cr) * NSEQ + k0 + kc;
            *(us8*)dst = o0;
            *(us8*)(dst + 8) = o1;
        }
    }
}

// ---------------------------------------------------------------------------
// MFMA flash attention, one block per (b,h), 4 waves, wave w owns q-tiles
// {w, w+4, w+8, w+12}. K/V/bias staged ONCE per key-tile for all q-tiles.
// Bias (with phantom-key mask and 0.25 scale pre-folded into q) enters as the
// MFMA C operand from biasC. kf/vf frags hoisted per key-tile.
// Grid: blockIdx.x = h*64 + b  (h slowest -> 64 blocks share biasC[h] in L2).
// ---------------------------------------------------------------------------
__global__ __launch_bounds__(256, 2)
void attn_mfma_kernel(const u16* __restrict__ q, const u16* __restrict__ k,
                      const u16* __restrict__ vt, const float* __restrict__ biasC,
                      u16* __restrict__ io)
{
    __shared__ u16 Ks[64 * 16];        // [key][kd] contiguous (global_load_lds)
    __shared__ u16 Vs[64 * 68];        // [d][key] stride 68 (zero conflicts, r4)

    const int t    = threadIdx.x;
    const int w    = t >> 6;
    const int lane = t & 63;
    const int col  = lane & 15;
    const int quad = lane >> 4;
    const int h  = blockIdx.x >> 6;
    const int b  = blockIdx.x & 63;
    const int bh = b * NHEAD + h;

    // Q frags (q pre-scaled by 0.25 in GEMM epilogue), head-split layout
    short8_t qf[4];
    #pragma unroll
    for (int i = 0; i < 4; ++i) {
        int qt = w + 4 * i;
        qf[i] = (short8_t)0;
        if (qt < 13 && quad < 2) {
            int qq = qt * 16 + col; if (qq > 195) qq = 195;
            qf[i] = *(const short8_t*)(q + ((size_t)bh * N2SEQ + qq) * 16 + quad * 8);
        }
    }

    f32x4 O[4][4];
    float m[4], l[4];
    #pragma unroll
    for (int i = 0; i < 4; ++i) {
        m[i] = -3e38f; l[i] = 0.f;
        #pragma unroll
        for (int ns = 0; ns < 4; ++ns) O[i][ns] = (f32x4)0.0f;
    }

    const u16* vtb = vt + (size_t)bh * 64 * NSEQ;
    const u16* kb  = k + (size_t)bh * NSEQ * 16;

    for (int ti = 0; ti < 13; ++ti) {
        const int t0 = ti * 64;
        if (w < 2) {   // K stage: waves 0,1 -> 2 KB via global_load_lds
            int c = w * 64 + lane;
            int tok = t0 + (c >> 1); if (tok > 783) tok = 783;
            const u16* src = kb + (size_t)tok * 16 + (c & 1) * 8;
            char* dst = (char*)Ks + w * 1024;
            __builtin_amdgcn_global_load_lds(
                (const __attribute__((address_space(1))) void*)src,
                (__attribute__((address_space(3))) void*)dst, 16, 0, 0);
        }
        {   // V stage: all 256 threads; d = t>>2, 16 keys each
            int d = t >> 2, part = t & 3;
            const u16* src = vtb + (size_t)d * NSEQ;
            u16* dst = Vs + d * 68 + part * 16;
            int kk = t0 + part * 16;
            int k0a = kk     > 776 ? 776 : kk;
            int k1a = kk + 8 > 776 ? 776 : kk + 8;
            us8 v0 = *(const us8*)(src + k0a);
            us8 v1 = *(const us8*)(src + k1a);
            us4 a, bb2, c2, d2;
            a.x = v0[0]; a.y = v0[1]; a.z = v0[2]; a.w = v0[3];
            bb2.x = v0[4]; bb2.y = v0[5]; bb2.z = v0[6]; bb2.w = v0[7];
            c2.x = v1[0]; c2.y = v1[1]; c2.z = v1[2]; c2.w = v1[3];
            d2.x = v1[4]; d2.y = v1[5]; d2.z = v1[6]; d2.w = v1[7];
            *(us4*)(dst)      = a;
            *(us4*)(dst + 4)  = bb2;
            *(us4*)(dst + 8)  = c2;
            *(us4*)(dst + 12) = d2;
        }
        __syncthreads();

        // hoisted K frags (shared by all q-tiles)
        short8_t kf[4];
        #pragma unroll
        for (int ks = 0; ks < 4; ++ks) {
            kf[ks] = (short8_t)0;
            if (quad < 2)
                kf[ks] = *(const short8_t*)&Ks[(ks * 16 + col) * 16 + quad * 8];
        }
        // hoisted V frags (k-permuted; shared by all q-tiles)
        short8_t vf[4][2];
        #pragma unroll
        for (int ns = 0; ns < 4; ++ns)
            #pragma unroll
            for (int pr = 0; pr < 2; ++pr) {
                const u16* vrow = &Vs[(ns * 16 + col) * 68 + pr * 32 + quad * 4];
                us4 v0 = *(const us4*)vrow;
                us4 v1 = *(const us4*)(vrow + 16);
                short8_t vv;
                vv[0] = (short)v0.x; vv[1] = (short)v0.y; vv[2] = (short)v0.z; vv[3] = (short)v0.w;
                vv[4] = (short)v1.x; vv[5] = (short)v1.y; vv[6] = (short)v1.z; vv[7] = (short)v1.w;
                vf[ns][pr] = vv;
            }

        #pragma unroll
        for (int i = 0; i < 4; ++i) {
            int qt = w + 4 * i;
            if (qt < 13) {
                // S^T = K·Q'^T + biasC (bias/mask as accumulator init)
                f32x4 S[4];
                #pragma unroll
                for (int ks = 0; ks < 4; ++ks) {
                    f32x4 c = *(const f32x4*)(biasC +
                        ((((size_t)h * 13 + ti) * 4 + ks) * 13 + qt) * 256 + lane * 4);
                    S[ks] = __builtin_amdgcn_mfma_f32_16x16x32_bf16(kf[ks], qf[i], c, 0, 0, 0);
                }
                // online softmax (per column q)
                float p[16];
                float mt = -3e38f;
                #pragma unroll
                for (int ks = 0; ks < 4; ++ks)
                    #pragma unroll
                    for (int r = 0; r < 4; ++r) {
                        float lg = S[ks][r];
                        p[ks * 4 + r] = lg;
                        mt = fmaxf(mt, lg);
                    }
                mt = fmaxf(mt, __shfl_xor(mt, 16));
                mt = fmaxf(mt, __shfl_xor(mt, 32));
                float mnew = fmaxf(m[i], mt);
                float alpha = __expf(m[i] - mnew);
                m[i] = mnew;
                float s = 0.f;
                #pragma unroll
                for (int j = 0; j < 16; ++j) { p[j] = __expf(p[j] - mnew); s += p[j]; }
                s += __shfl_xor(s, 16);
                s += __shfl_xor(s, 32);
                l[i] = l[i] * alpha + s;

                float ar[4];
                #pragma unroll
                for (int r = 0; r < 4; ++r) ar[r] = __shfl(alpha, quad * 4 + r);
                #pragma unroll
                for (int ns = 0; ns < 4; ++ns)
                    #pragma unroll
                    for (int r = 0; r < 4; ++r) O[i][ns][r] *= ar[r];

                // pack P (k-permuted to match vf)
                short8_t pf[2];
                #pragma unroll
                for (int pr = 0; pr < 2; ++pr)
                    #pragma unroll
                    for (int j = 0; j < 8; ++j)
                        pf[pr][j] = (short)f2bf(p[(2 * pr + (j >> 2)) * 4 + (j & 3)]);

                #pragma unroll
                for (int ns = 0; ns < 4; ++ns)
                    #pragma unroll
                    for (int pr = 0; pr < 2; ++pr)
                        O[i][ns] = __builtin_amdgcn_mfma_f32_16x16x32_bf16(
                            pf[pr], vf[ns][pr], O[i][ns], 0, 0, 0);
            }
        }
        __syncthreads();
    }

    // epilogue: O/l + v_local (RMW io, flat [b][q][512] layout)
    #pragma unroll
    for (int i = 0; i < 4; ++i) {
        int qt = w + 4 * i;
        if (qt < 13) {
            float linv = 1.0f / l[i];
            float lr[4];
            #pragma unroll
            for (int r = 0; r < 4; ++r) lr[r] = __shfl(linv, quad * 4 + r);
            #pragma unroll
            for (int ns = 0; ns < 4; ++ns)
                #pragma unroll
                for (int r = 0; r < 4; ++r) {
                    int q2 = qt * 16 + quad * 4 + r;
                    if (q2 < N2SEQ) {
                        size_t a = ((size_t)(b * N2SEQ + q2) * DHID) + h * 64 + ns * 16 + col;
                        io[a] = f2bf(O[i][ns][r] * lr[r] + bf2f(io[a]));
                    }
                }
        }
    }
}

// ---------------------------------------------------------------------------
extern "C" void kernel_launch(void* const* d_in, const int* in_sizes, int n_in,
                              void* d_out, int out_size, void* d_ws, size_t ws_size,
                              hipStream_t stream)
{
    const float* x          = (const float*)d_in[0];
    const float* q_local_w  = (const float*)d_in[1];
    const float* q_local_b  = (const float*)d_in[2];
    const float* q_proj_w   = (const float*)d_in[3];
    const float* q_proj_b   = (const float*)d_in[4];
    const float* q_bn_s     = (const float*)d_in[5];
    const float* q_bn_b     = (const float*)d_in[6];
    const float* k_w        = (const float*)d_in[7];
    const float* k_b        = (const float*)d_in[8];
    const float* k_bn_s     = (const float*)d_in[9];
    const float* k_bn_b     = (const float*)d_in[10];
    const float* v_w        = (const float*)d_in[11];
    const float* v_b        = (const float*)d_in[12];
    const float* v_bn_s     = (const float*)d_in[13];
    const float* v_bn_b     = (const float*)d_in[14];
    const float* vloc_w     = (const float*)d_in[15];
    const float* vloc_b     = (const float*)d_in[16];
    const float* vloc_bn_s  = (const float*)d_in[17];
    const float* vloc_bn_b  = (const float*)d_in[18];
    const float* proj_w     = (const float*)d_in[19];
    const float* proj_b     = (const float*)d_in[20];
    const float* proj_bn_s  = (const float*)d_in[21];
    const float* proj_bn_b  = (const float*)d_in[22];
    const float* attn_bias  = (const float*)d_in[23];
    float* out = (float*)d_out;

    const int M1 = BATCH * NSEQ;    // 50176
    const int M2 = BATCH * N2SEQ;   // 12544

    // ---- workspace (bytes), ~138.6 MB ----
    // Region A time-shared: [xb | qin_bf] (phases 1-4) then vt (after QKV).
    char* p = (char*)d_ws;
    u16* xb     = (u16*)p;
    u16* qin_bf = (u16*)(p + 38535168);
    u16* vt     = (u16*)p;
    size_t off = 51380224;
    u16* kwt = (u16*)(p + off);
    u16* vwt = kwt + (size_t)CIN * 128;
    u16* qwt = vwt + (size_t)CIN * DHID;
    u16* pwt = qwt + (size_t)CIN * 128;
    off += 1376256;
    u16* kbuf = (u16*)(p + off);    off += (size_t)M1 * 128 * 2;
    u16* vbuf = (u16*)(p + off);    off += (size_t)M1 * DHID * 2;
    u16* qbuf = (u16*)(p + off);    off += (size_t)M2 * 128 * 2;
    u16* vloc_bf = (u16*)(p + off); off += (size_t)M2 * DHID * 2;
    float* biasC = (float*)(p + off); off += (size_t)NHEAD * 13 * 4 * 13 * 256 * 4;
    float* qsb  = (float*)(p + off);   // 256 floats: scaled q_bn_s | q_bn_b

    // 1. casts & prep
    {
        int n4 = M1 * CIN / 4;
        cast_bf16_kernel<<<dim3((n4 + 255) / 256), 256, 0, stream>>>(x, xb, n4);
    }
    castT_kernel<<<dim3((CIN * 128 + 255) / 256), 256, 0, stream>>>(k_w, kwt, CIN, 128);
    castT_kernel<<<dim3((CIN * DHID + 255) / 256), 256, 0, stream>>>(v_w, vwt, CIN, DHID);
    castT_kernel<<<dim3((CIN * 128 + 255) / 256), 256, 0, stream>>>(q_proj_w, qwt, CIN, 128);
    castT_kernel<<<dim3((DHID * 768 + 255) / 256), 256, 0, stream>>>(proj_w, pwt, DHID, 768);
    scale_qsb_kernel<<<dim3(1), 128, 0, stream>>>(q_bn_s, q_bn_b, qsb);
    {
        int items = NHEAD * 13 * 4 * 13 * 64;
        biasC_kernel<<<dim3((items + 255) / 256), 256, 0, stream>>>(attn_bias, biasC);
    }
    // 2. q_in (bf16)
    {
        int items = M2 * (CIN / 4);
        qin_kernel<<<dim3((items + 255) / 256), 256, 0, stream>>>(x, q_local_w, q_local_b, qin_bf);
    }
    // 3. GEMMs: k,q in head-split layout; v flat
    gemm_mfma_kernel<2><<<dim3(M1 / TM, 128 / TN), 256, 0, stream>>>(
        xb, kwt, k_b, k_bn_s, k_bn_b, kbuf, M1, 128, CIN, NSEQ);
    gemm_mfma_kernel<1><<<dim3(M1 / TM, DHID / TN), 256, 0, stream>>>(
        xb, vwt, v_b, v_bn_s, v_bn_b, vbuf, M1, DHID, CIN, 0);
    gemm_mfma_kernel<2><<<dim3(M2 / TM, 128 / TN), 256, 0, stream>>>(
        qin_bf, qwt, q_proj_b, qsb, qsb + 128, qbuf, M2, 128, CIN, N2SEQ);

    // 4. V transpose (overwrites region A — xb/qin_bf dead)
    vt_transpose_kernel<<<dim3(BATCH, 13, NHEAD), 256, 0, stream>>>(vbuf, vt);

    // 5. v_local (bf16 — attention adds into it)
    {
        int items = M2 * (DHID / 4);
        vloc_kernel<<<dim3((items + 255) / 256), 256, 0, stream>>>(
            vbuf, vloc_w, vloc_b, vloc_bn_s, vloc_bn_b, vloc_bf);
    }
    // 6. MFMA flash attention (one block per (b,h), h slowest)
    attn_mfma_kernel<<<dim3(NHEAD * BATCH), 256, 0, stream>>>(
        qbuf, kbuf, vt, biasC, vloc_bf);

    // 7. proj GEMM (fp32 out)
    gemm_mfma_kernel<0><<<dim3(M2 / TM, 768 / TN), 256, 0, stream>>>(
        vloc_bf, pwt, proj_b, proj_bn_s, proj_bn_b, out, M2, 768, DHID, 0);
}

// Round 6
// 416.267 us; speedup vs baseline: 2.6589x; 1.0164x over previous
//
#include <hip/hip_runtime.h>
#include <cstdint>

#define RES    28
#define RES2   14
#define NHEAD  8
#define KDIM   16
#define DV     64
#define DHID   512
#define NSEQ   784
#define N2SEQ  196
#define BATCH  64
#define CIN    384

typedef unsigned short u16;
typedef short  short8_t __attribute__((ext_vector_type(8)));
typedef float  f32x4  __attribute__((ext_vector_type(4)));
typedef u16    us4    __attribute__((ext_vector_type(4)));
typedef u16    us8    __attribute__((ext_vector_type(8)));

__device__ __forceinline__ u16 f2bf(float f) {
    uint32_t u = __float_as_uint(f);
    return (u16)((u + 0x7fffu + ((u >> 16) & 1u)) >> 16);   // RNE
}
__device__ __forceinline__ float bf2f(u16 h) {
    return __uint_as_float(((uint32_t)h) << 16);
}

// ---------------------------------------------------------------------------
// One prep kernel: all weight transposes->bf16 + concatenated epilogue vecs.
// kvwt[640][384] = [k_w^T | v_w^T]; qwt[128][384]; pwt[768][512];
// kv_eps[1920] = [k_b|v_b, k_bn_s|v_bn_s, k_bn_b|v_bn_b]; qsb[256] = 0.25*[s|b]
// ---------------------------------------------------------------------------
#define PREP_N (49152 + 196608 + 49152 + 393216 + 1920 + 256)
__global__ __launch_bounds__(256)
void prep_kernel(const float* __restrict__ k_w, const float* __restrict__ v_w,
                 const float* __restrict__ q_proj_w, const float* __restrict__ proj_w,
                 const float* __restrict__ k_b, const float* __restrict__ v_b,
                 const float* __restrict__ k_bn_s, const float* __restrict__ v_bn_s,
                 const float* __restrict__ k_bn_b, const float* __restrict__ v_bn_b,
                 const float* __restrict__ q_bn_s, const float* __restrict__ q_bn_b,
                 u16* __restrict__ kvwt, u16* __restrict__ qwt, u16* __restrict__ pwt,
                 float* __restrict__ kv_eps, float* __restrict__ qsb)
{
    int i = blockIdx.x * 256 + threadIdx.x;
    if (i >= PREP_N) return;
    if (i < 49152) {                       // k_w^T -> kvwt rows 0..127
        int n = i / 384, k = i % 384;
        kvwt[i] = f2bf(k_w[(size_t)k * 128 + n]);
        return;
    }
    i -= 49152;
    if (i < 196608) {                      // v_w^T -> kvwt rows 128..639
        int n = i / 384, k = i % 384;
        kvwt[49152 + i] = f2bf(v_w[(size_t)k * 512 + n]);
        return;
    }
    i -= 196608;
    if (i < 49152) {                       // q_proj_w^T
        int n = i / 384, k = i % 384;
        qwt[i] = f2bf(q_proj_w[(size_t)k * 128 + n]);
        return;
    }
    i -= 49152;
    if (i < 393216) {                      // proj_w^T
        int n = i / 512, k = i % 512;
        pwt[i] = f2bf(proj_w[(size_t)k * 768 + n]);
        return;
    }
    i -= 393216;
    if (i < 1920) {                        // concatenated kv epilogue vectors
        int which = i / 640, j = i % 640;
        const float* a = which == 0 ? (j < 128 ? k_b : v_b)
                       : which == 1 ? (j < 128 ? k_bn_s : v_bn_s)
                                    : (j < 128 ? k_bn_b : v_bn_b);
        kv_eps[i] = a[j < 128 ? j : j - 128];
        return;
    }
    i -= 1920;
    qsb[i] = 0.25f * (i < 128 ? q_bn_s[i] : q_bn_b[i - 128]);
}

// ---------------------------------------------------------------------------
// biasC: attention bias pre-arranged in MFMA C-fragment layout
// idx = (((h*13+ti)*4+ks)*13+qt)*64 + lane, f32x4 over r.
// key = ti*64+ks*16+quad*4+r, q = qt*16+col; invalid key/q -> -1e30 (mask).
// ---------------------------------------------------------------------------
__global__ __launch_bounds__(256)
void biasC_kernel(const float* __restrict__ bias, float* __restrict__ biasC)
{
    int tid = blockIdx.x * 256 + threadIdx.x;
    if (tid >= NHEAD * 13 * 4 * 13 * 64) return;
    int lane = tid & 63;
    int rem  = tid >> 6;
    int qt = rem % 13; rem /= 13;
    int ks = rem % 4;  rem /= 4;
    int ti = rem % 13;
    int h  = rem / 13;
    int col = lane & 15, quad = lane >> 4;
    int q = qt * 16 + col;
    float4 out;
    float* po = &out.x;
    #pragma unroll
    for (int r = 0; r < 4; ++r) {
        int key = ti * 64 + ks * 16 + quad * 4 + r;
        float v;
        if (key >= NSEQ || q >= N2SEQ) {
            v = -1e30f;
        } else {
            int pi = q / 14, pj = q % 14;
            int ku = key / 28, kw = key % 28;
            int d0 = 2 * pj - kw; if (d0 < 0) d0 = -d0;
            int d1 = 2 * pi - ku; if (d1 < 0) d1 = -d1;
            v = bias[h * NSEQ + d0 * 28 + d1];
        }
        po[r] = v;
    }
    ((float4*)biasC)[tid] = out;
}

// ---------------------------------------------------------------------------
// MFMA GEMM: out = epi(A[M,K] @ Bt[N,K]^T)
// A_FP32: A is fp32, converted to bf16 during LDS staging (kills cast pass).
// OUT_MODE: 0 fp32 flat; 1 bf16 flat; 2 bf16 head-split (rpb rows/batch);
//           3 fused kv: bn<128 -> head-split k into outp (rpb=NSEQ),
//                       bn>=128 -> bf16 flat [row][512] into out2 at col-128.
// ---------------------------------------------------------------------------
#define TM 128
#define TN 128
#define TK 32

template<int OUT_MODE, int A_FP32>
__global__ __launch_bounds__(256)
void gemm_mfma_kernel(const void* __restrict__ Av, const u16* __restrict__ Bt,
                      const float* __restrict__ bias, const float* __restrict__ scale,
                      const float* __restrict__ shift, void* __restrict__ outp,
                      u16* __restrict__ out2, int M, int N, int K, int rpb)
{
    __shared__ u16 As[TM * TK];
    __shared__ u16 Bs[TN * TK];

    const int t  = threadIdx.x;
    const int w  = t >> 6;
    const int li = t & 63;
    const int wm = w >> 1, wn = w & 1;
    const int bm = blockIdx.x * TM;
    const int bn = blockIdx.y * TN;
    const int m16 = li & 15;
    const int kg  = li >> 4;

    f32x4 acc[4][4];
    #pragma unroll
    for (int i = 0; i < 4; ++i)
        #pragma unroll
        for (int j = 0; j < 4; ++j) acc[i][j] = (f32x4)0.0f;

    for (int k0 = 0; k0 < K; k0 += TK) {
        #pragma unroll
        for (int i = 0; i < 2; ++i) {
            int c   = (w * 2 + i) * 64 + li;
            int row = c >> 2, kc = c & 3;
            if (A_FP32) {
                const float* ag = (const float*)Av + (size_t)(bm + row) * K + k0 + kc * 8;
                float4 a0 = *(const float4*)ag;
                float4 a1 = *(const float4*)(ag + 4);
                us8 vv;
                vv[0] = f2bf(a0.x); vv[1] = f2bf(a0.y); vv[2] = f2bf(a0.z); vv[3] = f2bf(a0.w);
                vv[4] = f2bf(a1.x); vv[5] = f2bf(a1.y); vv[6] = f2bf(a1.z); vv[7] = f2bf(a1.w);
                *(us8*)&As[(size_t)row * TK + kc * 8] = vv;
            } else {
                const u16* ag = (const u16*)Av + (size_t)(bm + row) * K + k0 + kc * 8;
                char* la = (char*)As + (size_t)(w * 2 + i) * 64 * 16;
                __builtin_amdgcn_global_load_lds(
                    (const __attribute__((address_space(1))) void*)ag,
                    (__attribute__((address_space(3))) void*)la, 16, 0, 0);
            }
            const u16* bg = Bt + (size_t)(bn + row) * K + k0 + kc * 8;
            char* lb = (char*)Bs + (size_t)(w * 2 + i) * 64 * 16;
            __builtin_amdgcn_global_load_lds(
                (const __attribute__((address_space(1))) void*)bg,
                (__attribute__((address_space(3))) void*)lb, 16, 0, 0);
        }
        __syncthreads();

        short8_t af[4], bf[4];
        #pragma unroll
        for (int mi = 0; mi < 4; ++mi)
            af[mi] = *(const short8_t*)&As[(wm * 64 + mi * 16 + m16) * TK + kg * 8];
        #pragma unroll
        for (int ni = 0; ni < 4; ++ni)
            bf[ni] = *(const short8_t*)&Bs[(wn * 64 + ni * 16 + m16) * TK + kg * 8];

        #pragma unroll
        for (int mi = 0; mi < 4; ++mi)
            #pragma unroll
            for (int ni = 0; ni < 4; ++ni)
                acc[mi][ni] = __builtin_amdgcn_mfma_f32_16x16x32_bf16(
                    af[mi], bf[ni], acc[mi][ni], 0, 0, 0);
        __syncthreads();
    }

    #pragma unroll
    for (int ni = 0; ni < 4; ++ni) {
        const int col = bn + wn * 64 + ni * 16 + m16;
        const float bi = bias[col], sc = scale[col], sh = shift[col];
        #pragma unroll
        for (int mi = 0; mi < 4; ++mi) {
            const int rbase = bm + wm * 64 + mi * 16 + kg * 4;
            #pragma unroll
            for (int r = 0; r < 4; ++r) {
                float val = (acc[mi][ni][r] + bi) * sc + sh;
                const int row = rbase + r;
                if (OUT_MODE == 0) {
                    ((float*)outp)[(size_t)row * N + col] = val;
                } else if (OUT_MODE == 1) {
                    ((u16*)outp)[(size_t)row * N + col] = f2bf(val);
                } else if (OUT_MODE == 2) {
                    int bb = row / rpb, tok = row % rpb;
                    int hh = col >> 4;
                    ((u16*)outp)[((size_t)(bb * NHEAD + hh) * rpb + tok) * 16 + (col & 15)] = f2bf(val);
                } else {   // fused kv
                    if (bn < 128) {
                        int bb = row / NSEQ, tok = row % NSEQ;
                        int hh = col >> 4;
                        ((u16*)outp)[((size_t)(bb * NHEAD + hh) * NSEQ + tok) * 16 + (col & 15)] = f2bf(val);
                    } else {
                        out2[(size_t)row * DHID + (col - 128)] = f2bf(val);
                    }
                }
            }
        }
    }
}

// ---------------------------------------------------------------------------
// q_in = dwconv3x3_s2_SAME(x) + q_local_b + x[::2,::2]   (fp32 in, bf16 out)
// ---------------------------------------------------------------------------
__global__ __launch_bounds__(256)
void qin_kernel(const float* __restrict__ x, const float* __restrict__ w,
                const float* __restrict__ b, u16* __restrict__ qin)
{
    const int C4 = CIN / 4;
    int idx = blockIdx.x * 256 + threadIdx.x;
    if (idx >= BATCH * RES2 * RES2 * C4) return;
    int c4 = idx % C4;
    int r  = idx / C4;
    int j  = r % RES2; r /= RES2;
    int i  = r % RES2;
    int bb = r / RES2;

    const float4* x4 = (const float4*)x;
    const float4* w4 = (const float4*)w;
    float4 acc = make_float4(0.f, 0.f, 0.f, 0.f);
    #pragma unroll
    for (int dy = 0; dy < 3; ++dy) {
        int iy = 2 * i + dy;
        if (iy >= RES) continue;
        #pragma unroll
        for (int dx = 0; dx < 3; ++dx) {
            int ix = 2 * j + dx;
            if (ix >= RES) continue;
            float4 xv = x4[((size_t)(bb * RES + iy) * RES + ix) * C4 + c4];
            float4 wv = w4[(dy * 3 + dx) * C4 + c4];
            acc.x += xv.x * wv.x; acc.y += xv.y * wv.y;
            acc.z += xv.z * wv.z; acc.w += xv.w * wv.w;
        }
    }
    float4 bv = ((const float4*)b)[c4];
    float4 xs = x4[((size_t)(bb * RES + 2 * i) * RES + 2 * j) * C4 + c4];
    us4 o;
    o.x = f2bf(acc.x + bv.x + xs.x);
    o.y = f2bf(acc.y + bv.y + xs.y);
    o.z = f2bf(acc.z + bv.z + xs.z);
    o.w = f2bf(acc.w + bv.w + xs.w);
    ((us4*)qin)[idx] = o;
}

// ---------------------------------------------------------------------------
// v_local = BN(dwconv3x3_s2(v)) : v bf16 in, bf16 out (attention RMWs this)
// ---------------------------------------------------------------------------
__global__ __launch_bounds__(256)
void vloc_kernel(const u16* __restrict__ v, const float* __restrict__ w,
                 const float* __restrict__ b, const float* __restrict__ s,
                 const float* __restrict__ sh, u16* __restrict__ out)
{
    const int C4 = DHID / 4;
    int idx = blockIdx.x * 256 + threadIdx.x;
    if (idx >= BATCH * RES2 * RES2 * C4) return;
    int c4 = idx % C4;
    int r  = idx / C4;
    int j  = r % RES2; r /= RES2;
    int i  = r % RES2;
    int bb = r / RES2;

    const us4* v4 = (const us4*)v;
    const float4* w4 = (const float4*)w;
    float4 acc = make_float4(0.f, 0.f, 0.f, 0.f);
    #pragma unroll
    for (int dy = 0; dy < 3; ++dy) {
        int iy = 2 * i + dy;
        if (iy >= RES) continue;
        #pragma unroll
        for (int dx = 0; dx < 3; ++dx) {
            int ix = 2 * j + dx;
            if (ix >= RES) continue;
            us4 xu = v4[((size_t)(bb * RES + iy) * RES + ix) * C4 + c4];
            float4 wv = w4[(dy * 3 + dx) * C4 + c4];
            acc.x += bf2f(xu.x) * wv.x; acc.y += bf2f(xu.y) * wv.y;
            acc.z += bf2f(xu.z) * wv.z; acc.w += bf2f(xu.w) * wv.w;
        }
    }
    float4 bv = ((const float4*)b)[c4];
    float4 sv = ((const float4*)s)[c4];
    float4 hv = ((const float4*)sh)[c4];
    us4 o;
    o.x = f2bf((acc.x + bv.x) * sv.x + hv.x);
    o.y = f2bf((acc.y + bv.y) * sv.y + hv.y);
    o.z = f2bf((acc.z + bv.z) * sv.z + hv.z);
    o.w = f2bf((acc.w + bv.w) * sv.w + hv.w);
    ((us4*)out)[idx] = o;
}

// ---------------------------------------------------------------------------
// V transpose: vbuf[b][token(784)][512] -> vt[b][h][d(64)][token(784)]
// ---------------------------------------------------------------------------
__global__ __launch_bounds__(256)
void vt_transpose_kernel(const u16* __restrict__ vbuf, u16* __restrict__ vt)
{
    __shared__ u16 tile[64][66];
    const int t  = threadIdx.x;
    const int b  = blockIdx.x;
    const int k0 = blockIdx.y * 64;
    const int h  = blockIdx.z;

    {
        int kr = t >> 2, cc = (t & 3) * 16;
        int key = k0 + kr;
        if (key < NSEQ) {
            const u16* src = vbuf + ((size_t)b * NSEQ + key) * DHID + h * 64 + cc;
            us8 v0 = *(const us8*)src;
            us8 v1 = *(const us8*)(src + 8);
            #pragma unroll
            for (int i = 0; i < 8; ++i) { tile[kr][cc + i] = v0[i]; tile[kr][cc + 8 + i] = v1[i]; }
        }
    }
    __syncthreads();
    {
        int cr = t >> 2, kc = (t & 3) * 16;
        if (k0 + kc < NSEQ) {
            us8 o0, o1;
            #pragma unroll
            for (int i = 0; i < 8; ++i) { o0[i] = tile[kc + i][cr]; o1[i] = tile[kc + 8 + i][cr]; }
            u16* dst = vt + (((size_t)b * NHEAD + h) * 64 + cr) * NSEQ + k0 + kc;
            *(us8*)dst = o0;
            *(us8*)(dst + 8) = o1;
        }
    }
}

// ---------------------------------------------------------------------------
// MFMA flash attention, split-q x2.
// blockIdx.x = (h*64 + b)*2 + par; 4 waves; wave w owns q-tiles
// {w + 4*(par*2+i)} for i in {0,1}. K/V staged once per key-tile per block;
// the par pair is adjacent in dispatch -> shares K/V through L2/L3.
// Bias+mask (0.25 scale pre-folded into q) enters as MFMA C operand (biasC).
// ---------------------------------------------------------------------------
__global__ __launch_bounds__(256, 2)
void attn_mfma_kernel(const u16* __restrict__ q, const u16* __restrict__ k,
                      const u16* __restrict__ vt, const float* __restrict__ biasC,
                      u16* __restrict__ io)
{
    __shared__ u16 Ks[64 * 16];        // [key][kd] contiguous (global_load_lds)
    __shared__ u16 Vs[64 * 68];        // [d][key] stride 68 (zero conflicts)

    const int t    = threadIdx.x;
    const int w    = t >> 6;
    const int lane = t & 63;
    const int col  = lane & 15;
    const int quad = lane >> 4;
    const int par = blockIdx.x & 1;
    const int bhx = blockIdx.x >> 1;
    const int h  = bhx >> 6;
    const int b  = bhx & 63;
    const int bh = b * NHEAD + h;

    // Q frags (q pre-scaled by 0.25), head-split layout
    short8_t qf[2];
    #pragma unroll
    for (int i = 0; i < 2; ++i) {
        int qt = w + 4 * (par * 2 + i);
        qf[i] = (short8_t)0;
        if (qt < 13 && quad < 2) {
            int qq = qt * 16 + col; if (qq > 195) qq = 195;
            qf[i] = *(const short8_t*)(q + ((size_t)bh * N2SEQ + qq) * 16 + quad * 8);
        }
    }

    f32x4 O[2][4];
    float m[2], l[2];
    #pragma unroll
    for (int i = 0; i < 2; ++i) {
        m[i] = -3e38f; l[i] = 0.f;
        #pragma unroll
        for (int ns = 0; ns < 4; ++ns) O[i][ns] = (f32x4)0.0f;
    }

    const u16* vtb = vt + (size_t)bh * 64 * NSEQ;
    const u16* kb  = k + (size_t)bh * NSEQ * 16;

    for (int ti = 0; ti < 13; ++ti) {
        const int t0 = ti * 64;
        if (w < 2) {   // K stage: waves 0,1 -> 2 KB via global_load_lds
            int c = w * 64 + lane;
            int tok = t0 + (c >> 1); if (tok > 783) tok = 783;
            const u16* src = kb + (size_t)tok * 16 + (c & 1) * 8;
            char* dst = (char*)Ks + w * 1024;
            __builtin_amdgcn_global_load_lds(
                (const __attribute__((address_space(1))) void*)src,
                (__attribute__((address_space(3))) void*)dst, 16, 0, 0);
        }
        {   // V stage: all 256 threads; d = t>>2, 16 keys each
            int d = t >> 2, part = t & 3;
            const u16* src = vtb + (size_t)d * NSEQ;
            u16* dst = Vs + d * 68 + part * 16;
            int kk = t0 + part * 16;
            int k0a = kk     > 776 ? 776 : kk;
            int k1a = kk + 8 > 776 ? 776 : kk + 8;
            us8 v0 = *(const us8*)(src + k0a);
            us8 v1 = *(const us8*)(src + k1a);
            us4 a, bb2, c2, d2;
            a.x = v0[0]; a.y = v0[1]; a.z = v0[2]; a.w = v0[3];
            bb2.x = v0[4]; bb2.y = v0[5]; bb2.z = v0[6]; bb2.w = v0[7];
            c2.x = v1[0]; c2.y = v1[1]; c2.z = v1[2]; c2.w = v1[3];
            d2.x = v1[4]; d2.y = v1[5]; d2.z = v1[6]; d2.w = v1[7];
            *(us4*)(dst)      = a;
            *(us4*)(dst + 4)  = bb2;
            *(us4*)(dst + 8)  = c2;
            *(us4*)(dst + 12) = d2;
        }
        __syncthreads();

        // hoisted K frags
        short8_t kf[4];
        #pragma unroll
        for (int ks = 0; ks < 4; ++ks) {
            kf[ks] = (short8_t)0;
            if (quad < 2)
                kf[ks] = *(const short8_t*)&Ks[(ks * 16 + col) * 16 + quad * 8];
        }
        // hoisted V frags (k-permuted)
        short8_t vf[4][2];
        #pragma unroll
        for (int ns = 0; ns < 4; ++ns)
            #pragma unroll
            for (int pr = 0; pr < 2; ++pr) {
                const u16* vrow = &Vs[(ns * 16 + col) * 68 + pr * 32 + quad * 4];
                us4 v0 = *(const us4*)vrow;
                us4 v1 = *(const us4*)(vrow + 16);
                short8_t vv;
                vv[0] = (short)v0.x; vv[1] = (short)v0.y; vv[2] = (short)v0.z; vv[3] = (short)v0.w;
                vv[4] = (short)v1.x; vv[5] = (short)v1.y; vv[6] = (short)v1.z; vv[7] = (short)v1.w;
                vf[ns][pr] = vv;
            }

        #pragma unroll
        for (int i = 0; i < 2; ++i) {
            int qt = w + 4 * (par * 2 + i);
            if (qt < 13) {
                f32x4 S[4];
                #pragma unroll
                for (int ks = 0; ks < 4; ++ks) {
                    f32x4 c = *(const f32x4*)(biasC +
                        ((((size_t)h * 13 + ti) * 4 + ks) * 13 + qt) * 256 + lane * 4);
                    S[ks] = __builtin_amdgcn_mfma_f32_16x16x32_bf16(kf[ks], qf[i], c, 0, 0, 0);
                }
                float p[16];
                float mt = -3e38f;
                #pragma unroll
                for (int ks = 0; ks < 4; ++ks)
                    #pragma unroll
                    for (int r = 0; r < 4; ++r) {
                        float lg = S[ks][r];
                        p[ks * 4 + r] = lg;
                        mt = fmaxf(mt, lg);
                    }
                mt = fmaxf(mt, __shfl_xor(mt, 16));
                mt = fmaxf(mt, __shfl_xor(mt, 32));
                float mnew = fmaxf(m[i], mt);
                float alpha = __expf(m[i] - mnew);
                m[i] = mnew;
                float s = 0.f;
                #pragma unroll
                for (int j = 0; j < 16; ++j) { p[j] = __expf(p[j] - mnew); s += p[j]; }
                s += __shfl_xor(s, 16);
                s += __shfl_xor(s, 32);
                l[i] = l[i] * alpha + s;

                float ar[4];
                #pragma unroll
                for (int r = 0; r < 4; ++r) ar[r] = __shfl(alpha, quad * 4 + r);
                #pragma unroll
                for (int ns = 0; ns < 4; ++ns)
                    #pragma unroll
                    for (int r = 0; r < 4; ++r) O[i][ns][r] *= ar[r];

                short8_t pf[2];
                #pragma unroll
                for (int pr = 0; pr < 2; ++pr)
                    #pragma unroll
                    for (int j = 0; j < 8; ++j)
                        pf[pr][j] = (short)f2bf(p[(2 * pr + (j >> 2)) * 4 + (j & 3)]);

                #pragma unroll
                for (int ns = 0; ns < 4; ++ns)
                    #pragma unroll
                    for (int pr = 0; pr < 2; ++pr)
                        O[i][ns] = __builtin_amdgcn_mfma_f32_16x16x32_bf16(
                            pf[pr], vf[ns][pr], O[i][ns], 0, 0, 0);
            }
        }
        __syncthreads();
    }

    // epilogue: O/l + v_local (RMW io, flat [b][q][512])
    #pragma unroll
    for (int i = 0; i < 2; ++i) {
        int qt = w + 4 * (par * 2 + i);
        if (qt < 13) {
            float linv = 1.0f / l[i];
            float lr[4];
            #pragma unroll
            for (int r = 0; r < 4; ++r) lr[r] = __shfl(linv, quad * 4 + r);
            #pragma unroll
            for (int ns = 0; ns < 4; ++ns)
                #pragma unroll
                for (int r = 0; r < 4; ++r) {
                    int q2 = qt * 16 + quad * 4 + r;
                    if (q2 < N2SEQ) {
                        size_t a = ((size_t)(b * N2SEQ + q2) * DHID) + h * 64 + ns * 16 + col;
                        io[a] = f2bf(O[i][ns][r] * lr[r] + bf2f(io[a]));
                    }
                }
        }
    }
}

// ---------------------------------------------------------------------------
extern "C" void kernel_launch(void* const* d_in, const int* in_sizes, int n_in,
                              void* d_out, int out_size, void* d_ws, size_t ws_size,
                              hipStream_t stream)
{
    const float* x          = (const float*)d_in[0];
    const float* q_local_w  = (const float*)d_in[1];
    const float* q_local_b  = (const float*)d_in[2];
    const float* q_proj_w   = (const float*)d_in[3];
    const float* q_proj_b   = (const float*)d_in[4];
    const float* q_bn_s     = (const float*)d_in[5];
    const float* q_bn_b     = (const float*)d_in[6];
    const float* k_w        = (const float*)d_in[7];
    const float* k_b        = (const float*)d_in[8];
    const float* k_bn_s     = (const float*)d_in[9];
    const float* k_bn_b     = (const float*)d_in[10];
    const float* v_w        = (const float*)d_in[11];
    const float* v_b        = (const float*)d_in[12];
    const float* v_bn_s     = (const float*)d_in[13];
    const float* v_bn_b     = (const float*)d_in[14];
    const float* vloc_w     = (const float*)d_in[15];
    const float* vloc_b     = (const float*)d_in[16];
    const float* vloc_bn_s  = (const float*)d_in[17];
    const float* vloc_bn_b  = (const float*)d_in[18];
    const float* proj_w     = (const float*)d_in[19];
    const float* proj_b     = (const float*)d_in[20];
    const float* proj_bn_s  = (const float*)d_in[21];
    const float* proj_bn_b  = (const float*)d_in[22];
    const float* attn_bias  = (const float*)d_in[23];
    float* out = (float*)d_out;

    const int M1 = BATCH * NSEQ;    // 50176
    const int M2 = BATCH * N2SEQ;   // 12544

    // ---- workspace (bytes), ~88 MB ----
    // Region A time-shared: qin_bf (phases 1-3) then vt (after q GEMM).
    char* p = (char*)d_ws;
    u16* qin_bf = (u16*)p;                         // 9,633,792
    u16* vt     = (u16*)p;                         // 51,380,224 (overlays)
    size_t off = 51380224;
    u16* kvwt = (u16*)(p + off);  off += 640 * 384 * 2;       // 491,520
    u16* qwt  = (u16*)(p + off);  off += 128 * 384 * 2;       //  98,304
    u16* pwt  = (u16*)(p + off);  off += 768 * 512 * 2;       // 786,432
    float* kv_eps = (float*)(p + off); off += 1920 * 4;
    float* qsb    = (float*)(p + off); off += 256 * 4;
    u16* kbuf = (u16*)(p + off);    off += (size_t)M1 * 128 * 2;
    u16* vbuf = (u16*)(p + off);    off += (size_t)M1 * DHID * 2;
    u16* qbuf = (u16*)(p + off);    off += (size_t)M2 * 128 * 2;
    u16* vloc_bf = (u16*)(p + off); off += (size_t)M2 * DHID * 2;
    float* biasC = (float*)(p + off);

    // 1. prep (weights/eps) + biasC
    prep_kernel<<<dim3((PREP_N + 255) / 256), 256, 0, stream>>>(
        k_w, v_w, q_proj_w, proj_w, k_b, v_b, k_bn_s, v_bn_s, k_bn_b, v_bn_b,
        q_bn_s, q_bn_b, kvwt, qwt, pwt, kv_eps, qsb);
    {
        int items = NHEAD * 13 * 4 * 13 * 64;
        biasC_kernel<<<dim3((items + 255) / 256), 256, 0, stream>>>(attn_bias, biasC);
    }
    // 2. q_in (bf16)
    {
        int items = M2 * (CIN / 4);
        qin_kernel<<<dim3((items + 255) / 256), 256, 0, stream>>>(x, q_local_w, q_local_b, qin_bf);
    }
    // 3. fused k+v GEMM (fp32 A staged->bf16), then q GEMM
    gemm_mfma_kernel<3, 1><<<dim3(M1 / TM, 640 / TN), 256, 0, stream>>>(
        x, kvwt, kv_eps, kv_eps + 640, kv_eps + 1280, kbuf, vbuf, M1, 640, CIN, NSEQ);
    gemm_mfma_kernel<2, 0><<<dim3(M2 / TM, 128 / TN), 256, 0, stream>>>(
        qin_bf, qwt, q_proj_b, qsb, qsb + 128, qbuf, nullptr, M2, 128, CIN, N2SEQ);

    // 4. V transpose (overwrites region A — qin_bf dead)
    vt_transpose_kernel<<<dim3(BATCH, 13, NHEAD), 256, 0, stream>>>(vbuf, vt);

    // 5. v_local (bf16 — attention adds into it)
    {
        int items = M2 * (DHID / 4);
        vloc_kernel<<<dim3((items + 255) / 256), 256, 0, stream>>>(
            vbuf, vloc_w, vloc_b, vloc_bn_s, vloc_bn_b, vloc_bf);
    }
    // 6. MFMA flash attention, split-q x2 (par interleaved for L2 sharing)
    attn_mfma_kernel<<<dim3(NHEAD * BATCH * 2), 256, 0, stream>>>(
        qbuf, kbuf, vt, biasC, vloc_bf);

    // 7. proj GEMM (fp32 out)
    gemm_mfma_kernel<0, 0><<<dim3(M2 / TM, 768 / TN), 256, 0, stream>>>(
        vloc_bf, pwt, proj_b, proj_bn_s, proj_bn_b, out, nullptr, M2, 768, DHID, 0);
}